// Round 16
// baseline (205.673 us; speedup 1.0000x reference)
//
#include <hip/hip_runtime.h>
#include <hip/hip_bf16.h>

#define BB 4
#define SS 1024
#define DD 1024
#define HH 16

typedef __attribute__((ext_vector_type(8))) short bf16x8;
typedef __attribute__((ext_vector_type(4))) float f32x4;
typedef unsigned int u32;
typedef unsigned long long u64;

__device__ __forceinline__ ushort f2bf(float f) {
    u32 u = __builtin_bit_cast(u32, f);
    u32 r = (u + 0x7fffu + ((u >> 16) & 1u)) >> 16;
    return (ushort)r;
}
__device__ __forceinline__ float bf2f(ushort h) {
    return __builtin_bit_cast(float, (u32)h << 16);
}

__device__ __forceinline__ void gload16(const ushort* g, ushort* l) {
    __builtin_amdgcn_global_load_lds(
        (const __attribute__((address_space(1))) u32*)(const void*)g,
        (__attribute__((address_space(3))) u32*)(void*)l, 16, 0, 0);
}

// ---------------- convert f32 -> bf16 hi + lo residual (q and k fused) ----------------
__global__ __launch_bounds__(256) void cvt_split2(
    const float* __restrict__ q, const float* __restrict__ k,
    ushort* __restrict__ qh, ushort* __restrict__ ql,
    ushort* __restrict__ kh, ushort* __restrict__ kl) {
    int bid = blockIdx.x;
    const float* in;
    ushort *hi, *lo;
    if (bid < 4096) { in = q; hi = qh; lo = ql; }
    else            { in = k; hi = kh; lo = kl; bid -= 4096; }
    int i = (bid * 256 + threadIdx.x) * 4;
    float4 v = *(const float4*)(in + i);
    ushort4 h, l;
    float* pv = (float*)&v;
    ushort* ph = (ushort*)&h;
    ushort* pl = (ushort*)&l;
#pragma unroll
    for (int j = 0; j < 4; ++j) {
        ushort hh = f2bf(pv[j]);
        ph[j] = hh;
        pl[j] = f2bf(pv[j] - bf2f(hh));
    }
    *(ushort4*)(hi + i) = h;
    *(ushort4*)(lo + i) = l;
}

// ---------------- transpose W (f32 DxD) -> bf16 W^T hi/lo ----------------
__global__ __launch_bounds__(256) void transposeW_split(
    const float* __restrict__ Wq, const float* __restrict__ Wk,
    ushort* __restrict__ WqTh, ushort* __restrict__ WqTl,
    ushort* __restrict__ WkTh, ushort* __restrict__ WkTl) {
    __shared__ float tile[64][65];
    const float* W = blockIdx.z ? Wk : Wq;
    ushort* WTh = blockIdx.z ? WkTh : WqTh;
    ushort* WTl = blockIdx.z ? WkTl : WqTl;
    int kb = blockIdx.y * 64, nb = blockIdx.x * 64;
    int tid = threadIdx.x;
    int tx = tid & 63, ty = tid >> 6;
#pragma unroll
    for (int i = 0; i < 16; ++i) {
        int kl = ty * 16 + i;
        tile[kl][tx] = W[(size_t)(kb + kl) * DD + nb + tx];
    }
    __syncthreads();
#pragma unroll
    for (int i = 0; i < 16; ++i) {
        int nl = ty * 16 + i;
        float v = tile[tx][nl];
        ushort hh = f2bf(v);
        size_t idx = (size_t)(nb + nl) * DD + kb + tx;
        WTh[idx] = hh;
        WTl[idx] = f2bf(v - bf2f(hh));
    }
}

// ---------------- pack mask to bits ----------------
__global__ __launch_bounds__(256) void pack_mask(const int* __restrict__ mask,
                                                 u64* __restrict__ bits, int nwords) {
    int gw = (int)((blockIdx.x * 256 + threadIdx.x) >> 6);
    int lane = threadIdx.x & 63;
    if (gw < nwords) {
        int v = mask[(size_t)gw * 64 + lane];
        u64 m = __ballot(v != 0);
        if (lane == 0) bits[gw] = m;
    }
}

// ---------------- transpose k_hi per head-tile into tiled kT ----------------
__global__ __launch_bounds__(256) void transposeK(const ushort* __restrict__ kh,
                                                  ushort* __restrict__ kT) {
    __shared__ ushort t[64 * 66];
    int blk = blockIdx.x;
    const ushort* src = kh + (size_t)blk * 4096;
    ushort* dst = kT + (size_t)blk * 4096;
    int tid = threadIdx.x;
#pragma unroll
    for (int i = 0; i < 2; ++i) {
        int c = tid + 256 * i;
        int r = c >> 3, col = (c & 7) << 3;
        uint4 v = *(const uint4*)(src + (size_t)c * 8);
        const uint* pv = (const uint*)&v;
        *(uint*)(t + r * 66 + col + 0) = pv[0];
        *(uint*)(t + r * 66 + col + 2) = pv[1];
        *(uint*)(t + r * 66 + col + 4) = pv[2];
        *(uint*)(t + r * 66 + col + 6) = pv[3];
    }
    __syncthreads();
#pragma unroll
    for (int i = 0; i < 2; ++i) {
        int c = tid + 256 * i;
        int d = c >> 3, k0 = (c & 7) << 3;
        uint4 o;
        ushort* po = (ushort*)&o;
#pragma unroll
        for (int j = 0; j < 8; ++j) po[j] = t[(k0 + j) * 66 + d];
        *(uint4*)(dst + d * 64 + k0) = o;
    }
}

// swizzled LDS frag address (ushort units): row rr, 16B-block bi
#define SWZ(rr, bi) (((rr) << 6) + ((((bi) ^ ((rr) & 7))) << 3))

// ---------------- split-precision projection GEMM, q & k fused via blockIdx.z ----------
__global__ __launch_bounds__(256) void gemm_proj_f(
    const ushort* __restrict__ Aq_h, const ushort* __restrict__ Aq_l,
    const ushort* __restrict__ Ak_h, const ushort* __restrict__ Ak_l,
    const ushort* __restrict__ Bq_h, const ushort* __restrict__ Bq_l,
    const ushort* __restrict__ Bk_h, const ushort* __restrict__ Bk_l,
    const float* __restrict__ bq, const float* __restrict__ bk,
    const float* __restrict__ wcomb,
    ushort* __restrict__ Cq_hi, ushort* __restrict__ Cq_lo, ushort* __restrict__ Cw,
    ushort* __restrict__ Ck_hi, ushort* __restrict__ Ck_lo, int mode_base) {
    __shared__ __align__(16) ushort Ash[64 * 64];
    __shared__ __align__(16) ushort Asl[64 * 64];
    __shared__ __align__(16) ushort Bsh[128 * 64];
    __shared__ __align__(16) ushort Bsl[128 * 64];
    const int mode = blockIdx.z + mode_base;
    const ushort* Ah = mode ? Ak_h : Aq_h;
    const ushort* Al = mode ? Ak_l : Aq_l;
    const ushort* Bh = mode ? Bk_h : Bq_h;
    const ushort* Bl = mode ? Bk_l : Bq_l;
    const float* bias = mode ? bk : bq;
    ushort* Chi = mode ? Ck_hi : Cq_hi;
    ushort* Clo = mode ? Ck_lo : Cq_lo;
    const int tn = blockIdx.x, tm = blockIdx.y;
    const int tid = threadIdx.x, lane = tid & 63, w = tid >> 6;
    const int lr = lane >> 4, lc = lane & 15;
    const int srow = lane >> 3;                       // 0..7 within chunk
    const int sblk = (lane & 7) ^ ((lane >> 3) & 7);  // swizzled 16B block
    f32x4 acc[8];
#pragma unroll
    for (int n = 0; n < 8; ++n) acc[n] = (f32x4){0.f, 0.f, 0.f, 0.f};

    for (int kt = 0; kt < DD; kt += 64) {
        __syncthreads();
#pragma unroll
        for (int i = 0; i < 2; ++i) {
            int ch = (w << 1) + i;                    // chunk 0..7 (8 rows each)
            int row = (ch << 3) + srow;               // 0..63
            size_t g = (size_t)(tm * 64 + row) * DD + kt + sblk * 8;
            gload16(Ah + g, Ash + ch * 512);
            gload16(Al + g, Asl + ch * 512);
        }
#pragma unroll
        for (int i = 0; i < 4; ++i) {
            int ch = (w << 2) + i;                    // chunk 0..15
            int row = (ch << 3) + srow;               // 0..127
            size_t g = (size_t)(tn * 128 + row) * DD + kt + sblk * 8;
            gload16(Bh + g, Bsh + ch * 512);
            gload16(Bl + g, Bsl + ch * 512);
        }
        __syncthreads();
#pragma unroll
        for (int t = 0; t < 2; ++t) {
            int aoff = SWZ(w * 16 + lc, t * 4 + lr);
            bf16x8 afh = *(const bf16x8*)(Ash + aoff);
            bf16x8 afl = *(const bf16x8*)(Asl + aoff);
#pragma unroll
            for (int n = 0; n < 8; ++n) {
                int boff = SWZ(n * 16 + lc, t * 4 + lr);
                bf16x8 bfh = *(const bf16x8*)(Bsh + boff);
                bf16x8 bfl = *(const bf16x8*)(Bsl + boff);
                acc[n] = __builtin_amdgcn_mfma_f32_16x16x32_bf16(afh, bfh, acc[n], 0, 0, 0);
                acc[n] = __builtin_amdgcn_mfma_f32_16x16x32_bf16(afh, bfl, acc[n], 0, 0, 0);
                acc[n] = __builtin_amdgcn_mfma_f32_16x16x32_bf16(afl, bfh, acc[n], 0, 0, 0);
            }
        }
    }
#pragma unroll
    for (int n = 0; n < 8; ++n) {
        int gcol = tn * 128 + n * 16 + lc;
#pragma unroll
        for (int r = 0; r < 4; ++r) {
            int grow = tm * 64 + w * 16 + lr * 4 + r;
            float v = acc[n][r] + bias[gcol];
            size_t idx = (size_t)grow * DD + gcol;
            ushort hh = f2bf(v);
            Chi[idx] = hh;
            Clo[idx] = f2bf(v - bf2f(hh));
            if (mode == 0) Cw[idx] = f2bf(v * wcomb[(grow >> 6) & 15]);
        }
    }
}

// ---------------- FAT kernel (512 thr): comb (blocks 0..255) || attn (256..767) ------
// attn: 8 waves, 128 q-rows/block, LDS 48 KB; P (8 waves x 1KB) aliases kh+kl (both
// dead after QK^T), guarded by RAW s_barrier (no vmcnt drain).
__global__ __launch_bounds__(512) void attn_comb(
    const ushort* __restrict__ qh_, const ushort* __restrict__ ql_,
    const ushort* __restrict__ kh_, const ushort* __restrict__ kl_,
    const ushort* __restrict__ kT_, const u64* __restrict__ mbits,
    float* __restrict__ ctx,
    const ushort* __restrict__ Aq, const ushort* __restrict__ Bk,
    const float* __restrict__ bcomb, float* __restrict__ probs) {
    __shared__ __align__(16) ushort shm[24576];  // 49,152 B
    const int bid = blockIdx.x;
    const int tid = threadIdx.x, lane = tid & 63, w = tid >> 6;  // w 0..7
    const int lr = lane >> 4, lc = lane & 15;

    if (bid < 256) {
        // ---------------- combined-scores GEMM, 8-wave split (64x32 wave tiles) -------
        ushort* As = shm;           // 128x64 swizzled
        ushort* Bs = shm + 8192;
        const int tn = bid & 7, tm = (bid >> 3) & 7, bz = bid >> 6;
        const ushort* Ab = Aq + (size_t)bz * SS * DD;
        const ushort* Bb = Bk + (size_t)bz * SS * DD;
        const int wm = w >> 2, wn = w & 3;  // wave tile: rows wm*64, cols wn*32
        f32x4 acc[4][2];
#pragma unroll
        for (int m = 0; m < 4; ++m)
#pragma unroll
            for (int n = 0; n < 2; ++n) acc[m][n] = (f32x4){0.f, 0.f, 0.f, 0.f};

        for (int h = 0; h < HH; ++h) {
            __syncthreads();
            const ushort* Asrc = Ab + (size_t)h * 65536 + tm * 8192;
            const ushort* Bsrc = Bb + (size_t)h * 65536 + tn * 8192;
#pragma unroll
            for (int i = 0; i < 2; ++i) {
                int ch = (w << 1) + i;                      // chunk 0..15 (1024B)
                int row = (ch << 3) + (lane >> 3);          // 0..127
                int blkk = (lane & 7) ^ ((lane >> 3) & 7);  // swizzled 16B block
                size_t g = (size_t)row * 64 + blkk * 8;
                gload16(Asrc + g, As + ch * 512);
                gload16(Bsrc + g, Bs + ch * 512);
            }
            __syncthreads();
#pragma unroll
            for (int t = 0; t < 2; ++t) {
                bf16x8 af[4], bfr[2];
#pragma unroll
                for (int m = 0; m < 4; ++m)
                    af[m] = *(const bf16x8*)(As + SWZ(wm * 64 + m * 16 + lc, t * 4 + lr));
#pragma unroll
                for (int n = 0; n < 2; ++n)
                    bfr[n] = *(const bf16x8*)(Bs + SWZ(wn * 32 + n * 16 + lc, t * 4 + lr));
#pragma unroll
                for (int m = 0; m < 4; ++m)
#pragma unroll
                    for (int n = 0; n < 2; ++n)
                        acc[m][n] = __builtin_amdgcn_mfma_f32_16x16x32_bf16(af[m], bfr[n], acc[m][n], 0, 0, 0);
            }
        }
        float b0 = bcomb[0];
#pragma unroll
        for (int m = 0; m < 4; ++m) {
            int grow0 = tm * 128 + wm * 64 + m * 16 + lr * 4;
#pragma unroll
            for (int n = 0; n < 2; ++n) {
                int gcol = tn * 128 + wn * 32 + n * 16 + lc;
#pragma unroll
                for (int r = 0; r < 4; ++r)
                    probs[(size_t)bz * SS * SS + (size_t)(grow0 + r) * SS + gcol] = acc[m][n][r] + b0;
            }
        }
        return;
    }

    // ---------------- flash attention (V = K): r15-proven per-wave body, 8 waves -----
    const int abid = bid - 256;
    const int qt = abid & 7, h = (abid >> 3) & 15, b = abid >> 7;
    ushort* KbBase = shm;          // [2][3][4096] = 48 KB
    const int bh = b * HH + h;
    const size_t headbase = (size_t)bh * (SS * 64);

    auto KB = [&](int buf, int j) -> ushort* { return KbBase + (buf * 3 + j) * 4096; };
    auto stage = [&](int buf, int kt) {
        int ch = w;                                  // each wave: one 8-row chunk
        int row = (ch << 3) + (lane >> 3);
        int blkk = (lane & 7) ^ ((lane >> 3) & 7);
        size_t g = ((size_t)bh * 16 + kt) * 4096 + (size_t)row * 64 + blkk * 8;
        gload16(kh_ + g, KB(buf, 0) + ch * 512);
        gload16(kl_ + g, KB(buf, 1) + ch * 512);
        gload16(kT_ + g, KB(buf, 2) + ch * 512);
    };

    bf16x8 qfh[2], qfl[2];
    {
        size_t rowoff = headbase + (size_t)(qt * 128 + w * 16 + lc) * 64;
#pragma unroll
        for (int t = 0; t < 2; ++t) {
            qfh[t] = *(const bf16x8*)(qh_ + rowoff + t * 32 + lr * 8);
            qfl[t] = *(const bf16x8*)(ql_ + rowoff + t * 32 + lr * 8);
        }
    }
    f32x4 acc[4];
#pragma unroll
    for (int dt = 0; dt < 4; ++dt) acc[dt] = (f32x4){0.f, 0.f, 0.f, 0.f};
    float mrow[4] = {-3e38f, -3e38f, -3e38f, -3e38f};
    float lsum[4] = {0.f, 0.f, 0.f, 0.f};  // per-lane partial (scale is row-uniform)

    stage(0, 0);
    __syncthreads();
    int cur = 0;

    for (int kt = 0; kt < 16; ++kt) {
        if (kt < 15) stage(cur ^ 1, kt + 1);  // prefetch next (hidden under compute)

        const ushort* Bh = KB(cur, 0);
        const ushort* Bl = KB(cur, 1);
        const ushort* Vt = KB(cur, 2);

        // QK^T (split precision): s = qh*kh + qh*kl + ql*kh
        f32x4 sc[4];
#pragma unroll
        for (int nt = 0; nt < 4; ++nt) {
            f32x4 z = (f32x4){0.f, 0.f, 0.f, 0.f};
            __builtin_amdgcn_s_setprio(1);
#pragma unroll
            for (int t = 0; t < 2; ++t) {
                bf16x8 kfh = *(const bf16x8*)(Bh + SWZ(nt * 16 + lc, t * 4 + lr));
                bf16x8 kfl = *(const bf16x8*)(Bl + SWZ(nt * 16 + lc, t * 4 + lr));
                z = __builtin_amdgcn_mfma_f32_16x16x32_bf16(qfh[t], kfh, z, 0, 0, 0);
                z = __builtin_amdgcn_mfma_f32_16x16x32_bf16(qfh[t], kfl, z, 0, 0, 0);
                z = __builtin_amdgcn_mfma_f32_16x16x32_bf16(qfl[t], kfh, z, 0, 0, 0);
            }
            __builtin_amdgcn_s_setprio(0);
            sc[nt] = z;
        }

        // mask + online softmax: rmax shfl (proven), rsum deferred to per-lane partial
#pragma unroll
        for (int r = 0; r < 4; ++r) {
            u64 wbit = mbits[((size_t)b * SS + qt * 128 + w * 16 + lr * 4 + r) * 16 + kt];
            float rmax = -3e38f;
#pragma unroll
            for (int nt = 0; nt < 4; ++nt) {
                int kkloc = nt * 16 + lc;
                float v = sc[nt][r];
                v = ((wbit >> kkloc) & 1ULL) ? v : -3e38f;
                sc[nt][r] = v;
                rmax = fmaxf(rmax, v);
            }
#pragma unroll
            for (int d2 = 1; d2 < 16; d2 <<= 1) rmax = fmaxf(rmax, __shfl_xor(rmax, d2, 64));
            float mnew = fmaxf(mrow[r], rmax);
            float scale = __expf(mrow[r] - mnew);
            float rsum = 0.f;
#pragma unroll
            for (int nt = 0; nt < 4; ++nt) {
                float p = __expf(sc[nt][r] - mnew);
                sc[nt][r] = p;
                rsum += p;
            }
            lsum[r] = lsum[r] * scale + rsum;  // per-lane; summed across lanes at end
            mrow[r] = mnew;
#pragma unroll
            for (int dt = 0; dt < 4; ++dt) acc[dt][r] *= scale;
        }

        // RAW barrier: all waves' kh/kl reads done before P overwrites them.
        // (No vmcnt drain -> the stage() prefetch stays in flight.)
        __builtin_amdgcn_s_barrier();
        __builtin_amdgcn_sched_barrier(0);

        // P -> aliased kh+kl region (wave-private 16x64, SWZ-swizzled), RNE pack
        ushort* P = KB(cur, 0) + w * 1024;  // w 0..7 spans kh (4K) + kl (4K)
#pragma unroll
        for (int nt = 0; nt < 4; ++nt)
#pragma unroll
            for (int r = 0; r < 4; ++r) {
                int lrow = lr * 4 + r;
                P[SWZ(lrow, nt * 2 + (lc >> 3)) + (lc & 7)] = f2bf(sc[nt][r]);
            }
        asm volatile("s_waitcnt lgkmcnt(0)" ::: "memory");
        __builtin_amdgcn_sched_barrier(0);

        bf16x8 pf[2];
#pragma unroll
        for (int t = 0; t < 2; ++t)
            pf[t] = *(const bf16x8*)(P + SWZ(lc, t * 4 + lr));

        // PV: context += P @ K_tile (V = K hi, from pre-transposed kT)
        __builtin_amdgcn_s_setprio(1);
#pragma unroll
        for (int dt = 0; dt < 4; ++dt) {
#pragma unroll
            for (int t = 0; t < 2; ++t) {
                bf16x8 vf = *(const bf16x8*)(Vt + SWZ(dt * 16 + lc, t * 4 + lr));
                acc[dt] = __builtin_amdgcn_mfma_f32_16x16x32_bf16(pf[t], vf, acc[dt], 0, 0, 0);
            }
        }
        __builtin_amdgcn_s_setprio(0);

        if (kt < 15) __syncthreads();  // drains vmcnt (stage) + syncs buffers
        cur ^= 1;
    }

    // epilogue: one lsum reduction across the 16-lane row group (proven shfl butterfly)
#pragma unroll
    for (int r = 0; r < 4; ++r) {
#pragma unroll
        for (int d2 = 1; d2 < 16; d2 <<= 1) lsum[r] += __shfl_xor(lsum[r], d2, 64);
        float inv = (lsum[r] > 0.f) ? 1.f / lsum[r] : 0.f;
        int q = qt * 128 + w * 16 + lr * 4 + r;
#pragma unroll
        for (int dt = 0; dt < 4; ++dt)
            ctx[(((size_t)bh) * SS + q) * 64 + dt * 16 + lc] = acc[dt][r] * inv;
    }
}

// ---------------- row softmax for probs ----------------
__global__ __launch_bounds__(256) void softmax_rows(float* __restrict__ data) {
    int w = threadIdx.x >> 6, lane = threadIdx.x & 63;
    float* p = data + ((size_t)blockIdx.x * 4 + w) * SS;
    float4 v[4];
    float mx = -3e38f;
#pragma unroll
    for (int i = 0; i < 4; ++i) {
        v[i] = *(const float4*)(p + i * 256 + lane * 4);
        mx = fmaxf(mx, fmaxf(fmaxf(v[i].x, v[i].y), fmaxf(v[i].z, v[i].w)));
    }
#pragma unroll
    for (int d2 = 1; d2 < 64; d2 <<= 1) mx = fmaxf(mx, __shfl_xor(mx, d2, 64));
    float sum = 0.f;
#pragma unroll
    for (int i = 0; i < 4; ++i) {
        v[i].x = __expf(v[i].x - mx);
        v[i].y = __expf(v[i].y - mx);
        v[i].z = __expf(v[i].z - mx);
        v[i].w = __expf(v[i].w - mx);
        sum += v[i].x + v[i].y + v[i].z + v[i].w;
    }
#pragma unroll
    for (int d2 = 1; d2 < 64; d2 <<= 1) sum += __shfl_xor(sum, d2, 64);
    float inv = 1.f / sum;
#pragma unroll
    for (int i = 0; i < 4; ++i) {
        v[i].x *= inv; v[i].y *= inv; v[i].z *= inv; v[i].w *= inv;
        *(float4*)(p + i * 256 + lane * 4) = v[i];
    }
}

extern "C" void kernel_launch(void* const* d_in, const int* in_sizes, int n_in,
                              void* d_out, int out_size, void* d_ws, size_t ws_size,
                              hipStream_t stream) {
    const float* query = (const float*)d_in[0];
    const float* key   = (const float*)d_in[1];
    const int*   mask  = (const int*)d_in[2];
    const float* Wq    = (const float*)d_in[3];
    const float* bq    = (const float*)d_in[4];
    const float* Wk    = (const float*)d_in[5];
    const float* bk    = (const float*)d_in[6];
    const float* wcomb = (const float*)d_in[7];
    const float* bcomb = (const float*)d_in[8];
    float* probs = (float*)d_out;                          // (B,S,S)
    float* ctx   = (float*)d_out + (size_t)BB * SS * SS;   // (B,H,S,DK) flat

    char* ws = (char*)d_ws;
    const size_t MB = 1ull << 20;
    ushort* query_hi = (ushort*)(ws);             // [0,8)
    ushort* query_lo = (ushort*)(ws + 8 * MB);    // [8,16)
    ushort* key_hi   = (ushort*)(ws + 16 * MB);   // [16,24)
    ushort* key_lo   = (ushort*)(ws + 24 * MB);   // [24,32)
    ushort* WqTh     = (ushort*)(ws + 32 * MB);   // [32,34)
    ushort* WqTl     = (ushort*)(ws + 34 * MB);   // [34,36)
    ushort* WkTh     = (ushort*)(ws + 36 * MB);   // [36,38)
    ushort* WkTl     = (ushort*)(ws + 38 * MB);   // [38,40)
    ushort* qw_bf    = (ushort*)(ws + 40 * MB);   // [40,48)
    ushort* q_hi     = (ushort*)(ws + 48 * MB);   // [48,56)
    ushort* q_lo     = (ushort*)(ws + 56 * MB);   // [56,64)
    u64*    mbits    = (u64*)(ws + 64 * MB);      // [64,64.5)
    ushort* kT       = (ushort*)(ws + 65 * MB);   // [65,73)

    const bool bigws = ws_size >= 90 * MB;
    ushort* k_hi = bigws ? (ushort*)(ws + 73 * MB) : (ushort*)(ws);
    ushort* k_lo = bigws ? (ushort*)(ws + 81 * MB) : (ushort*)(ws + 8 * MB);

    cvt_split2<<<8192, 256, 0, stream>>>(query, key, query_hi, query_lo, key_hi, key_lo);
    transposeW_split<<<dim3(16, 16, 2), 256, 0, stream>>>(Wq, Wk, WqTh, WqTl, WkTh, WkTl);
    pack_mask<<<16384, 256, 0, stream>>>(mask, mbits, BB * SS * (SS / 64));

    if (bigws) {
        gemm_proj_f<<<dim3(8, 64, 2), 256, 0, stream>>>(
            query_hi, query_lo, key_hi, key_lo, WqTh, WqTl, WkTh, WkTl,
            bq, bk, wcomb, q_hi, q_lo, qw_bf, k_hi, k_lo, 0);
    } else {
        gemm_proj_f<<<dim3(8, 64, 1), 256, 0, stream>>>(
            query_hi, query_lo, key_hi, key_lo, WqTh, WqTl, WkTh, WkTl,
            bq, bk, wcomb, q_hi, q_lo, qw_bf, k_hi, k_lo, 0);
        gemm_proj_f<<<dim3(8, 64, 1), 256, 0, stream>>>(
            query_hi, query_lo, key_hi, key_lo, WqTh, WqTl, WkTh, WkTl,
            bq, bk, wcomb, q_hi, q_lo, qw_bf, k_hi, k_lo, 1);
    }

    transposeK<<<1024, 256, 0, stream>>>(k_hi, kT);

    // fat kernel (512 thr): blocks 0..255 = combined-scores GEMM, 256..767 = attention
    attn_comb<<<768, 512, 0, stream>>>(q_hi, q_lo, k_hi, k_lo, kT, mbits, ctx,
                                       qw_bf, k_hi, bcomb, probs);

    softmax_rows<<<1024, 256, 0, stream>>>(probs);
    (void)in_sizes; (void)n_in; (void)out_size;
}

// Round 17
// 196.882 us; speedup vs baseline: 1.0447x; 1.0447x over previous
//
#include <hip/hip_runtime.h>
#include <hip/hip_bf16.h>

#define BB 4
#define SS 1024
#define DD 1024
#define HH 16

typedef __attribute__((ext_vector_type(8))) short bf16x8;
typedef __attribute__((ext_vector_type(4))) float f32x4;
typedef unsigned int u32;
typedef unsigned long long u64;

__device__ __forceinline__ ushort f2bf(float f) {
    u32 u = __builtin_bit_cast(u32, f);
    u32 r = (u + 0x7fffu + ((u >> 16) & 1u)) >> 16;
    return (ushort)r;
}
__device__ __forceinline__ float bf2f(ushort h) {
    return __builtin_bit_cast(float, (u32)h << 16);
}

__device__ __forceinline__ void gload16(const ushort* g, ushort* l) {
    __builtin_amdgcn_global_load_lds(
        (const __attribute__((address_space(1))) u32*)(const void*)g,
        (__attribute__((address_space(3))) u32*)(void*)l, 16, 0, 0);
}

// ---------------- convert f32 -> bf16 hi + lo residual (q and k fused) ----------------
__global__ __launch_bounds__(256) void cvt_split2(
    const float* __restrict__ q, const float* __restrict__ k,
    ushort* __restrict__ qh, ushort* __restrict__ ql,
    ushort* __restrict__ kh, ushort* __restrict__ kl) {
    int bid = blockIdx.x;
    const float* in;
    ushort *hi, *lo;
    if (bid < 4096) { in = q; hi = qh; lo = ql; }
    else            { in = k; hi = kh; lo = kl; bid -= 4096; }
    int i = (bid * 256 + threadIdx.x) * 4;
    float4 v = *(const float4*)(in + i);
    ushort4 h, l;
    float* pv = (float*)&v;
    ushort* ph = (ushort*)&h;
    ushort* pl = (ushort*)&l;
#pragma unroll
    for (int j = 0; j < 4; ++j) {
        ushort hh = f2bf(pv[j]);
        ph[j] = hh;
        pl[j] = f2bf(pv[j] - bf2f(hh));
    }
    *(ushort4*)(hi + i) = h;
    *(ushort4*)(lo + i) = l;
}

// ---------------- transpose W (f32 DxD) -> bf16 W^T hi/lo ----------------
__global__ __launch_bounds__(256) void transposeW_split(
    const float* __restrict__ Wq, const float* __restrict__ Wk,
    ushort* __restrict__ WqTh, ushort* __restrict__ WqTl,
    ushort* __restrict__ WkTh, ushort* __restrict__ WkTl) {
    __shared__ float tile[64][65];
    const float* W = blockIdx.z ? Wk : Wq;
    ushort* WTh = blockIdx.z ? WkTh : WqTh;
    ushort* WTl = blockIdx.z ? WkTl : WqTl;
    int kb = blockIdx.y * 64, nb = blockIdx.x * 64;
    int tid = threadIdx.x;
    int tx = tid & 63, ty = tid >> 6;
#pragma unroll
    for (int i = 0; i < 16; ++i) {
        int kl = ty * 16 + i;
        tile[kl][tx] = W[(size_t)(kb + kl) * DD + nb + tx];
    }
    __syncthreads();
#pragma unroll
    for (int i = 0; i < 16; ++i) {
        int nl = ty * 16 + i;
        float v = tile[tx][nl];
        ushort hh = f2bf(v);
        size_t idx = (size_t)(nb + nl) * DD + kb + tx;
        WTh[idx] = hh;
        WTl[idx] = f2bf(v - bf2f(hh));
    }
}

// ---------------- pack mask to bits ----------------
__global__ __launch_bounds__(256) void pack_mask(const int* __restrict__ mask,
                                                 u64* __restrict__ bits, int nwords) {
    int gw = (int)((blockIdx.x * 256 + threadIdx.x) >> 6);
    int lane = threadIdx.x & 63;
    if (gw < nwords) {
        int v = mask[(size_t)gw * 64 + lane];
        u64 m = __ballot(v != 0);
        if (lane == 0) bits[gw] = m;
    }
}

// ---------------- transpose k_hi per head-tile into tiled kT ----------------
__global__ __launch_bounds__(256) void transposeK(const ushort* __restrict__ kh,
                                                  ushort* __restrict__ kT) {
    __shared__ ushort t[64 * 66];
    int blk = blockIdx.x;
    const ushort* src = kh + (size_t)blk * 4096;
    ushort* dst = kT + (size_t)blk * 4096;
    int tid = threadIdx.x;
#pragma unroll
    for (int i = 0; i < 2; ++i) {
        int c = tid + 256 * i;
        int r = c >> 3, col = (c & 7) << 3;
        uint4 v = *(const uint4*)(src + (size_t)c * 8);
        const uint* pv = (const uint*)&v;
        *(uint*)(t + r * 66 + col + 0) = pv[0];
        *(uint*)(t + r * 66 + col + 2) = pv[1];
        *(uint*)(t + r * 66 + col + 4) = pv[2];
        *(uint*)(t + r * 66 + col + 6) = pv[3];
    }
    __syncthreads();
#pragma unroll
    for (int i = 0; i < 2; ++i) {
        int c = tid + 256 * i;
        int d = c >> 3, k0 = (c & 7) << 3;
        uint4 o;
        ushort* po = (ushort*)&o;
#pragma unroll
        for (int j = 0; j < 8; ++j) po[j] = t[(k0 + j) * 66 + d];
        *(uint4*)(dst + d * 64 + k0) = o;
    }
}

// swizzled LDS frag address (ushort units): row rr, 16B-block bi
#define SWZ(rr, bi) (((rr) << 6) + ((((bi) ^ ((rr) & 7))) << 3))

// ---------------- split-precision projection GEMM, q & k fused via blockIdx.z ----------
__global__ __launch_bounds__(256) void gemm_proj_f(
    const ushort* __restrict__ Aq_h, const ushort* __restrict__ Aq_l,
    const ushort* __restrict__ Ak_h, const ushort* __restrict__ Ak_l,
    const ushort* __restrict__ Bq_h, const ushort* __restrict__ Bq_l,
    const ushort* __restrict__ Bk_h, const ushort* __restrict__ Bk_l,
    const float* __restrict__ bq, const float* __restrict__ bk,
    const float* __restrict__ wcomb,
    ushort* __restrict__ Cq_hi, ushort* __restrict__ Cq_lo, ushort* __restrict__ Cw,
    ushort* __restrict__ Ck_hi, ushort* __restrict__ Ck_lo, int mode_base) {
    __shared__ __align__(16) ushort Ash[64 * 64];
    __shared__ __align__(16) ushort Asl[64 * 64];
    __shared__ __align__(16) ushort Bsh[128 * 64];
    __shared__ __align__(16) ushort Bsl[128 * 64];
    const int mode = blockIdx.z + mode_base;
    const ushort* Ah = mode ? Ak_h : Aq_h;
    const ushort* Al = mode ? Ak_l : Aq_l;
    const ushort* Bh = mode ? Bk_h : Bq_h;
    const ushort* Bl = mode ? Bk_l : Bq_l;
    const float* bias = mode ? bk : bq;
    ushort* Chi = mode ? Ck_hi : Cq_hi;
    ushort* Clo = mode ? Ck_lo : Cq_lo;
    const int tn = blockIdx.x, tm = blockIdx.y;
    const int tid = threadIdx.x, lane = tid & 63, w = tid >> 6;
    const int lr = lane >> 4, lc = lane & 15;
    const int srow = lane >> 3;                       // 0..7 within chunk
    const int sblk = (lane & 7) ^ ((lane >> 3) & 7);  // swizzled 16B block
    f32x4 acc[8];
#pragma unroll
    for (int n = 0; n < 8; ++n) acc[n] = (f32x4){0.f, 0.f, 0.f, 0.f};

    for (int kt = 0; kt < DD; kt += 64) {
        __syncthreads();
#pragma unroll
        for (int i = 0; i < 2; ++i) {
            int ch = (w << 1) + i;                    // chunk 0..7 (8 rows each)
            int row = (ch << 3) + srow;               // 0..63
            size_t g = (size_t)(tm * 64 + row) * DD + kt + sblk * 8;
            gload16(Ah + g, Ash + ch * 512);
            gload16(Al + g, Asl + ch * 512);
        }
#pragma unroll
        for (int i = 0; i < 4; ++i) {
            int ch = (w << 2) + i;                    // chunk 0..15
            int row = (ch << 3) + srow;               // 0..127
            size_t g = (size_t)(tn * 128 + row) * DD + kt + sblk * 8;
            gload16(Bh + g, Bsh + ch * 512);
            gload16(Bl + g, Bsl + ch * 512);
        }
        __syncthreads();
#pragma unroll
        for (int t = 0; t < 2; ++t) {
            int aoff = SWZ(w * 16 + lc, t * 4 + lr);
            bf16x8 afh = *(const bf16x8*)(Ash + aoff);
            bf16x8 afl = *(const bf16x8*)(Asl + aoff);
#pragma unroll
            for (int n = 0; n < 8; ++n) {
                int boff = SWZ(n * 16 + lc, t * 4 + lr);
                bf16x8 bfh = *(const bf16x8*)(Bsh + boff);
                bf16x8 bfl = *(const bf16x8*)(Bsl + boff);
                acc[n] = __builtin_amdgcn_mfma_f32_16x16x32_bf16(afh, bfh, acc[n], 0, 0, 0);
                acc[n] = __builtin_amdgcn_mfma_f32_16x16x32_bf16(afh, bfl, acc[n], 0, 0, 0);
                acc[n] = __builtin_amdgcn_mfma_f32_16x16x32_bf16(afl, bfh, acc[n], 0, 0, 0);
            }
        }
    }
#pragma unroll
    for (int n = 0; n < 8; ++n) {
        int gcol = tn * 128 + n * 16 + lc;
#pragma unroll
        for (int r = 0; r < 4; ++r) {
            int grow = tm * 64 + w * 16 + lr * 4 + r;
            float v = acc[n][r] + bias[gcol];
            size_t idx = (size_t)grow * DD + gcol;
            ushort hh = f2bf(v);
            Chi[idx] = hh;
            Clo[idx] = f2bf(v - bf2f(hh));
            if (mode == 0) Cw[idx] = f2bf(v * wcomb[(grow >> 6) & 15]);
        }
    }
}

// ---------------- FAT kernel: gemm_comb (blocks 0..255) || attn (blocks 256..1279) ----
// attn LDS = 40 KB (4 blocks/CU): kh,kT double-buffered; kl SINGLE-buffered, restaged
// after the RAW s_barrier (all QK^T kl-reads proven done); P aliases dead kh.
__global__ __launch_bounds__(256) void attn_comb(
    const ushort* __restrict__ qh_, const ushort* __restrict__ ql_,
    const ushort* __restrict__ kh_, const ushort* __restrict__ kl_,
    const ushort* __restrict__ kT_, const u64* __restrict__ mbits,
    float* __restrict__ ctx,
    const ushort* __restrict__ Aq, const ushort* __restrict__ Bk,
    const float* __restrict__ bcomb, float* __restrict__ probs) {
    __shared__ __align__(16) ushort shm[20480];  // 40,960 B
    const int bid = blockIdx.x;
    const int tid = threadIdx.x, lane = tid & 63, w = tid >> 6;
    const int lr = lane >> 4, lc = lane & 15;

    if (bid < 256) {
        // ---------------- combined-scores GEMM (swizzled staging; r13-r15-proven) -----
        ushort* As = shm;           // 128x64 swizzled (16 KB)
        ushort* Bs = shm + 8192;    // (16 KB)
        const int tn = bid & 7, tm = (bid >> 3) & 7, bz = bid >> 6;
        const ushort* Ab = Aq + (size_t)bz * SS * DD;
        const ushort* Bb = Bk + (size_t)bz * SS * DD;
        const int wm = w >> 1, wn = w & 1;
        f32x4 acc[4][4];
#pragma unroll
        for (int m = 0; m < 4; ++m)
#pragma unroll
            for (int n = 0; n < 4; ++n) acc[m][n] = (f32x4){0.f, 0.f, 0.f, 0.f};

        for (int h = 0; h < HH; ++h) {
            __syncthreads();
            const ushort* Asrc = Ab + (size_t)h * 65536 + tm * 8192;
            const ushort* Bsrc = Bb + (size_t)h * 65536 + tn * 8192;
#pragma unroll
            for (int i = 0; i < 4; ++i) {
                int ch = (w << 2) + i;                      // chunk 0..15 (1024B)
                int row = (ch << 3) + (lane >> 3);          // 0..127
                int blkk = (lane & 7) ^ ((lane >> 3) & 7);  // swizzled 16B block
                size_t g = (size_t)row * 64 + blkk * 8;
                gload16(Asrc + g, As + ch * 512);
                gload16(Bsrc + g, Bs + ch * 512);
            }
            __syncthreads();
#pragma unroll
            for (int t = 0; t < 2; ++t) {
                bf16x8 af[4], bfr[4];
#pragma unroll
                for (int m = 0; m < 4; ++m)
                    af[m] = *(const bf16x8*)(As + SWZ(wm * 64 + m * 16 + lc, t * 4 + lr));
#pragma unroll
                for (int n = 0; n < 4; ++n)
                    bfr[n] = *(const bf16x8*)(Bs + SWZ(wn * 64 + n * 16 + lc, t * 4 + lr));
#pragma unroll
                for (int m = 0; m < 4; ++m)
#pragma unroll
                    for (int n = 0; n < 4; ++n)
                        acc[m][n] = __builtin_amdgcn_mfma_f32_16x16x32_bf16(af[m], bfr[n], acc[m][n], 0, 0, 0);
            }
        }
        float b0 = bcomb[0];
#pragma unroll
        for (int m = 0; m < 4; ++m) {
            int grow0 = tm * 128 + wm * 64 + m * 16 + lr * 4;
#pragma unroll
            for (int n = 0; n < 4; ++n) {
                int gcol = tn * 128 + wn * 64 + n * 16 + lc;
#pragma unroll
                for (int r = 0; r < 4; ++r)
                    probs[(size_t)bz * SS * SS + (size_t)(grow0 + r) * SS + gcol] = acc[m][n][r] + b0;
            }
        }
        return;
    }

    // ---------------- flash attention (V = K): r15-proven math, kl single-buffered ---
    const int abid = bid - 256;
    const int qt = abid & 15, h = (abid >> 4) & 15, b = abid >> 8;
    const int bh = b * HH + h;
    const size_t headbase = (size_t)bh * (SS * 64);

    // LDS map (ushort units): KH[2] @ 0,4096 ; KL @ 8192 ; KT[2] @ 12288,16384
    auto KH = [&](int buf) -> ushort* { return shm + buf * 4096; };
    ushort* KL = shm + 8192;
    auto KT = [&](int buf) -> ushort* { return shm + 12288 + buf * 4096; };

    const int srow = lane >> 3;
    const int sblk = (lane & 7) ^ ((lane >> 3) & 7);
    auto stage_hT = [&](int buf, int kt) {
#pragma unroll
        for (int i = 0; i < 2; ++i) {
            int ch = (w << 1) + i;
            int row = (ch << 3) + srow;
            size_t g = ((size_t)bh * 16 + kt) * 4096 + (size_t)row * 64 + sblk * 8;
            gload16(kh_ + g, KH(buf) + ch * 512);
            gload16(kT_ + g, KT(buf) + ch * 512);
        }
    };
    auto stage_l = [&](int kt) {
#pragma unroll
        for (int i = 0; i < 2; ++i) {
            int ch = (w << 1) + i;
            int row = (ch << 3) + srow;
            size_t g = ((size_t)bh * 16 + kt) * 4096 + (size_t)row * 64 + sblk * 8;
            gload16(kl_ + g, KL + ch * 512);
        }
    };

    bf16x8 qfh[2], qfl[2];
    {
        size_t rowoff = headbase + (size_t)(qt * 64 + w * 16 + lc) * 64;
#pragma unroll
        for (int t = 0; t < 2; ++t) {
            qfh[t] = *(const bf16x8*)(qh_ + rowoff + t * 32 + lr * 8);
            qfl[t] = *(const bf16x8*)(ql_ + rowoff + t * 32 + lr * 8);
        }
    }
    f32x4 acc[4];
#pragma unroll
    for (int dt = 0; dt < 4; ++dt) acc[dt] = (f32x4){0.f, 0.f, 0.f, 0.f};
    float mrow[4] = {-3e38f, -3e38f, -3e38f, -3e38f};
    float lsum[4] = {0.f, 0.f, 0.f, 0.f};  // per-lane partial (scale is row-uniform)

    stage_hT(0, 0);
    stage_l(0);
    __syncthreads();
    int cur = 0;

    for (int kt = 0; kt < 16; ++kt) {
        if (kt < 15) stage_hT(cur ^ 1, kt + 1);  // kh/kT prefetch (hidden under compute)

        const ushort* Bh = KH(cur);
        const ushort* Vt = KT(cur);

        // QK^T (split precision): s = qh*kh + qh*kl + ql*kh
        f32x4 sc[4];
#pragma unroll
        for (int nt = 0; nt < 4; ++nt) {
            f32x4 z = (f32x4){0.f, 0.f, 0.f, 0.f};
            __builtin_amdgcn_s_setprio(1);
#pragma unroll
            for (int t = 0; t < 2; ++t) {
                bf16x8 kfh = *(const bf16x8*)(Bh + SWZ(nt * 16 + lc, t * 4 + lr));
                bf16x8 kfl = *(const bf16x8*)(KL + SWZ(nt * 16 + lc, t * 4 + lr));
                z = __builtin_amdgcn_mfma_f32_16x16x32_bf16(qfh[t], kfh, z, 0, 0, 0);
                z = __builtin_amdgcn_mfma_f32_16x16x32_bf16(qfh[t], kfl, z, 0, 0, 0);
                z = __builtin_amdgcn_mfma_f32_16x16x32_bf16(qfl[t], kfh, z, 0, 0, 0);
            }
            __builtin_amdgcn_s_setprio(0);
            sc[nt] = z;
        }

        // mask + online softmax: rmax shfl (proven), rsum deferred to per-lane partial
#pragma unroll
        for (int r = 0; r < 4; ++r) {
            u64 wbit = mbits[((size_t)b * SS + qt * 64 + w * 16 + lr * 4 + r) * 16 + kt];
            float rmax = -3e38f;
#pragma unroll
            for (int nt = 0; nt < 4; ++nt) {
                int kkloc = nt * 16 + lc;
                float v = sc[nt][r];
                v = ((wbit >> kkloc) & 1ULL) ? v : -3e38f;
                sc[nt][r] = v;
                rmax = fmaxf(rmax, v);
            }
#pragma unroll
            for (int d2 = 1; d2 < 16; d2 <<= 1) rmax = fmaxf(rmax, __shfl_xor(rmax, d2, 64));
            float mnew = fmaxf(mrow[r], rmax);
            float scale = __expf(mrow[r] - mnew);
            float rsum = 0.f;
#pragma unroll
            for (int nt = 0; nt < 4; ++nt) {
                float p = __expf(sc[nt][r] - mnew);
                sc[nt][r] = p;
                rsum += p;
            }
            lsum[r] = lsum[r] * scale + rsum;  // per-lane; summed across lanes at end
            mrow[r] = mnew;
#pragma unroll
            for (int dt = 0; dt < 4; ++dt) acc[dt][r] *= scale;
        }

        // RAW barrier: all waves' kh AND kl reads done (QK^T complete everywhere).
        // (No vmcnt drain -> the stage_hT prefetch stays in flight.)
        __builtin_amdgcn_s_barrier();
        __builtin_amdgcn_sched_barrier(0);

        // kl for NEXT tile -> single KL buffer (safe after barrier); overlaps P+PV.
        if (kt < 15) stage_l(kt + 1);

        // P -> aliased kh slice (wave-private 16x64, SWZ-swizzled), RNE pack (proven)
        ushort* P = KH(cur) + w * 1024;
#pragma unroll
        for (int nt = 0; nt < 4; ++nt)
#pragma unroll
            for (int r = 0; r < 4; ++r) {
                int lrow = lr * 4 + r;
                P[SWZ(lrow, nt * 2 + (lc >> 3)) + (lc & 7)] = f2bf(sc[nt][r]);
            }
        asm volatile("s_waitcnt lgkmcnt(0)" ::: "memory");
        __builtin_amdgcn_sched_barrier(0);

        bf16x8 pf[2];
#pragma unroll
        for (int t = 0; t < 2; ++t)
            pf[t] = *(const bf16x8*)(P + SWZ(lc, t * 4 + lr));

        // PV: context += P @ K_tile (V = K hi, from pre-transposed kT)
        __builtin_amdgcn_s_setprio(1);
#pragma unroll
        for (int dt = 0; dt < 4; ++dt) {
#pragma unroll
            for (int t = 0; t < 2; ++t) {
                bf16x8 vf = *(const bf16x8*)(Vt + SWZ(dt * 16 + lc, t * 4 + lr));
                acc[dt] = __builtin_amdgcn_mfma_f32_16x16x32_bf16(pf[t], vf, acc[dt], 0, 0, 0);
            }
        }
        __builtin_amdgcn_s_setprio(0);

        if (kt < 15) __syncthreads();  // drains vmcnt (stage_hT + stage_l) + syncs
        cur ^= 1;
    }

    // epilogue: one lsum reduction across the 16-lane row group (proven shfl butterfly)
#pragma unroll
    for (int r = 0; r < 4; ++r) {
#pragma unroll
        for (int d2 = 1; d2 < 16; d2 <<= 1) lsum[r] += __shfl_xor(lsum[r], d2, 64);
        float inv = (lsum[r] > 0.f) ? 1.f / lsum[r] : 0.f;
        int q = qt * 64 + w * 16 + lr * 4 + r;
#pragma unroll
        for (int dt = 0; dt < 4; ++dt)
            ctx[(((size_t)bh) * SS + q) * 64 + dt * 16 + lc] = acc[dt][r] * inv;
    }
}

// ---------------- row softmax for probs ----------------
__global__ __launch_bounds__(256) void softmax_rows(float* __restrict__ data) {
    int w = threadIdx.x >> 6, lane = threadIdx.x & 63;
    float* p = data + ((size_t)blockIdx.x * 4 + w) * SS;
    float4 v[4];
    float mx = -3e38f;
#pragma unroll
    for (int i = 0; i < 4; ++i) {
        v[i] = *(const float4*)(p + i * 256 + lane * 4);
        mx = fmaxf(mx, fmaxf(fmaxf(v[i].x, v[i].y), fmaxf(v[i].z, v[i].w)));
    }
#pragma unroll
    for (int d2 = 1; d2 < 64; d2 <<= 1) mx = fmaxf(mx, __shfl_xor(mx, d2, 64));
    float sum = 0.f;
#pragma unroll
    for (int i = 0; i < 4; ++i) {
        v[i].x = __expf(v[i].x - mx);
        v[i].y = __expf(v[i].y - mx);
        v[i].z = __expf(v[i].z - mx);
        v[i].w = __expf(v[i].w - mx);
        sum += v[i].x + v[i].y + v[i].z + v[i].w;
    }
#pragma unroll
    for (int d2 = 1; d2 < 64; d2 <<= 1) sum += __shfl_xor(sum, d2, 64);
    float inv = 1.f / sum;
#pragma unroll
    for (int i = 0; i < 4; ++i) {
        v[i].x *= inv; v[i].y *= inv; v[i].z *= inv; v[i].w *= inv;
        *(float4*)(p + i * 256 + lane * 4) = v[i];
    }
}

extern "C" void kernel_launch(void* const* d_in, const int* in_sizes, int n_in,
                              void* d_out, int out_size, void* d_ws, size_t ws_size,
                              hipStream_t stream) {
    const float* query = (const float*)d_in[0];
    const float* key   = (const float*)d_in[1];
    const int*   mask  = (const int*)d_in[2];
    const float* Wq    = (const float*)d_in[3];
    const float* bq    = (const float*)d_in[4];
    const float* Wk    = (const float*)d_in[5];
    const float* bk    = (const float*)d_in[6];
    const float* wcomb = (const float*)d_in[7];
    const float* bcomb = (const float*)d_in[8];
    float* probs = (float*)d_out;                          // (B,S,S)
    float* ctx   = (float*)d_out + (size_t)BB * SS * SS;   // (B,H,S,DK) flat

    char* ws = (char*)d_ws;
    const size_t MB = 1ull << 20;
    ushort* query_hi = (ushort*)(ws);             // [0,8)
    ushort* query_lo = (ushort*)(ws + 8 * MB);    // [8,16)
    ushort* key_hi   = (ushort*)(ws + 16 * MB);   // [16,24)
    ushort* key_lo   = (ushort*)(ws + 24 * MB);   // [24,32)
    ushort* WqTh     = (ushort*)(ws + 32 * MB);   // [32,34)
    ushort* WqTl     = (ushort*)(ws + 34 * MB);   // [34,36)
    ushort* WkTh     = (ushort*)(ws + 36 * MB);   // [36,38)
    ushort* WkTl     = (ushort*)(ws + 38 * MB);   // [38,40)
    ushort* qw_bf    = (ushort*)(ws + 40 * MB);   // [40,48)
    ushort* q_hi     = (ushort*)(ws + 48 * MB);   // [48,56)
    ushort* q_lo     = (ushort*)(ws + 56 * MB);   // [56,64)
    u64*    mbits    = (u64*)(ws + 64 * MB);      // [64,64.5)
    ushort* kT       = (ushort*)(ws + 65 * MB);   // [65,73)

    const bool bigws = ws_size >= 90 * MB;
    ushort* k_hi = bigws ? (ushort*)(ws + 73 * MB) : (ushort*)(ws);
    ushort* k_lo = bigws ? (ushort*)(ws + 81 * MB) : (ushort*)(ws + 8 * MB);

    cvt_split2<<<8192, 256, 0, stream>>>(query, key, query_hi, query_lo, key_hi, key_lo);
    transposeW_split<<<dim3(16, 16, 2), 256, 0, stream>>>(Wq, Wk, WqTh, WqTl, WkTh, WkTl);
    pack_mask<<<16384, 256, 0, stream>>>(mask, mbits, BB * SS * (SS / 64));

    if (bigws) {
        gemm_proj_f<<<dim3(8, 64, 2), 256, 0, stream>>>(
            query_hi, query_lo, key_hi, key_lo, WqTh, WqTl, WkTh, WkTl,
            bq, bk, wcomb, q_hi, q_lo, qw_bf, k_hi, k_lo, 0);
    } else {
        gemm_proj_f<<<dim3(8, 64, 1), 256, 0, stream>>>(
            query_hi, query_lo, key_hi, key_lo, WqTh, WqTl, WkTh, WkTl,
            bq, bk, wcomb, q_hi, q_lo, qw_bf, k_hi, k_lo, 0);
        gemm_proj_f<<<dim3(8, 64, 1), 256, 0, stream>>>(
            query_hi, query_lo, key_hi, key_lo, WqTh, WqTl, WkTh, WkTl,
            bq, bk, wcomb, q_hi, q_lo, qw_bf, k_hi, k_lo, 1);
    }

    transposeK<<<1024, 256, 0, stream>>>(k_hi, kT);

    // fat kernel: blocks 0..255 = combined-scores GEMM, 256..1279 = attention
    attn_comb<<<1280, 256, 0, stream>>>(q_hi, q_lo, k_hi, k_lo, kT, mbits, ctx,
                                        qw_bf, k_hi, bcomb, probs);

    softmax_rows<<<1024, 256, 0, stream>>>(probs);
    (void)in_sizes; (void)n_in; (void)out_size;
}

// Round 18
// 195.974 us; speedup vs baseline: 1.0495x; 1.0046x over previous
//
#include <hip/hip_runtime.h>
#include <hip/hip_bf16.h>

#define BB 4
#define SS 1024
#define DD 1024
#define HH 16

typedef __attribute__((ext_vector_type(8))) short bf16x8;
typedef __attribute__((ext_vector_type(4))) float f32x4;
typedef unsigned int u32;
typedef unsigned long long u64;

__device__ __forceinline__ ushort f2bf(float f) {
    u32 u = __builtin_bit_cast(u32, f);
    u32 r = (u + 0x7fffu + ((u >> 16) & 1u)) >> 16;
    return (ushort)r;
}
__device__ __forceinline__ float bf2f(ushort h) {
    return __builtin_bit_cast(float, (u32)h << 16);
}

__device__ __forceinline__ void gload16(const ushort* g, ushort* l) {
    __builtin_amdgcn_global_load_lds(
        (const __attribute__((address_space(1))) u32*)(const void*)g,
        (__attribute__((address_space(3))) u32*)(void*)l, 16, 0, 0);
}

// ---------------- convert f32 -> bf16 hi + lo residual (q and k fused) ----------------
__global__ __launch_bounds__(256) void cvt_split2(
    const float* __restrict__ q, const float* __restrict__ k,
    ushort* __restrict__ qh, ushort* __restrict__ ql,
    ushort* __restrict__ kh, ushort* __restrict__ kl) {
    int bid = blockIdx.x;
    const float* in;
    ushort *hi, *lo;
    if (bid < 4096) { in = q; hi = qh; lo = ql; }
    else            { in = k; hi = kh; lo = kl; bid -= 4096; }
    int i = (bid * 256 + threadIdx.x) * 4;
    float4 v = *(const float4*)(in + i);
    ushort4 h, l;
    float* pv = (float*)&v;
    ushort* ph = (ushort*)&h;
    ushort* pl = (ushort*)&l;
#pragma unroll
    for (int j = 0; j < 4; ++j) {
        ushort hh = f2bf(pv[j]);
        ph[j] = hh;
        pl[j] = f2bf(pv[j] - bf2f(hh));
    }
    *(ushort4*)(hi + i) = h;
    *(ushort4*)(lo + i) = l;
}

// ---------------- transpose W (f32 DxD) -> bf16 W^T hi/lo ----------------
__global__ __launch_bounds__(256) void transposeW_split(
    const float* __restrict__ Wq, const float* __restrict__ Wk,
    ushort* __restrict__ WqTh, ushort* __restrict__ WqTl,
    ushort* __restrict__ WkTh, ushort* __restrict__ WkTl) {
    __shared__ float tile[64][65];
    const float* W = blockIdx.z ? Wk : Wq;
    ushort* WTh = blockIdx.z ? WkTh : WqTh;
    ushort* WTl = blockIdx.z ? WkTl : WqTl;
    int kb = blockIdx.y * 64, nb = blockIdx.x * 64;
    int tid = threadIdx.x;
    int tx = tid & 63, ty = tid >> 6;
#pragma unroll
    for (int i = 0; i < 16; ++i) {
        int kl = ty * 16 + i;
        tile[kl][tx] = W[(size_t)(kb + kl) * DD + nb + tx];
    }
    __syncthreads();
#pragma unroll
    for (int i = 0; i < 16; ++i) {
        int nl = ty * 16 + i;
        float v = tile[tx][nl];
        ushort hh = f2bf(v);
        size_t idx = (size_t)(nb + nl) * DD + kb + tx;
        WTh[idx] = hh;
        WTl[idx] = f2bf(v - bf2f(hh));
    }
}

// ---------------- pack mask to bits ----------------
__global__ __launch_bounds__(256) void pack_mask(const int* __restrict__ mask,
                                                 u64* __restrict__ bits, int nwords) {
    int gw = (int)((blockIdx.x * 256 + threadIdx.x) >> 6);
    int lane = threadIdx.x & 63;
    if (gw < nwords) {
        int v = mask[(size_t)gw * 64 + lane];
        u64 m = __ballot(v != 0);
        if (lane == 0) bits[gw] = m;
    }
}

// ---------------- transpose k_hi per head-tile into tiled kT ----------------
__global__ __launch_bounds__(256) void transposeK(const ushort* __restrict__ kh,
                                                  ushort* __restrict__ kT) {
    __shared__ ushort t[64 * 66];
    int blk = blockIdx.x;
    const ushort* src = kh + (size_t)blk * 4096;
    ushort* dst = kT + (size_t)blk * 4096;
    int tid = threadIdx.x;
#pragma unroll
    for (int i = 0; i < 2; ++i) {
        int c = tid + 256 * i;
        int r = c >> 3, col = (c & 7) << 3;
        uint4 v = *(const uint4*)(src + (size_t)c * 8);
        const uint* pv = (const uint*)&v;
        *(uint*)(t + r * 66 + col + 0) = pv[0];
        *(uint*)(t + r * 66 + col + 2) = pv[1];
        *(uint*)(t + r * 66 + col + 4) = pv[2];
        *(uint*)(t + r * 66 + col + 6) = pv[3];
    }
    __syncthreads();
#pragma unroll
    for (int i = 0; i < 2; ++i) {
        int c = tid + 256 * i;
        int d = c >> 3, k0 = (c & 7) << 3;
        uint4 o;
        ushort* po = (ushort*)&o;
#pragma unroll
        for (int j = 0; j < 8; ++j) po[j] = t[(k0 + j) * 66 + d];
        *(uint4*)(dst + d * 64 + k0) = o;
    }
}

// swizzled LDS frag address (ushort units): row rr, 16B-block bi
#define SWZ(rr, bi) (((rr) << 6) + ((((bi) ^ ((rr) & 7))) << 3))

// ---------------- split-precision projection GEMM, q & k fused via blockIdx.z ----------
__global__ __launch_bounds__(256) void gemm_proj_f(
    const ushort* __restrict__ Aq_h, const ushort* __restrict__ Aq_l,
    const ushort* __restrict__ Ak_h, const ushort* __restrict__ Ak_l,
    const ushort* __restrict__ Bq_h, const ushort* __restrict__ Bq_l,
    const ushort* __restrict__ Bk_h, const ushort* __restrict__ Bk_l,
    const float* __restrict__ bq, const float* __restrict__ bk,
    const float* __restrict__ wcomb,
    ushort* __restrict__ Cq_hi, ushort* __restrict__ Cq_lo, ushort* __restrict__ Cw,
    ushort* __restrict__ Ck_hi, ushort* __restrict__ Ck_lo, int mode_base) {
    __shared__ __align__(16) ushort Ash[64 * 64];
    __shared__ __align__(16) ushort Asl[64 * 64];
    __shared__ __align__(16) ushort Bsh[128 * 64];
    __shared__ __align__(16) ushort Bsl[128 * 64];
    const int mode = blockIdx.z + mode_base;
    const ushort* Ah = mode ? Ak_h : Aq_h;
    const ushort* Al = mode ? Ak_l : Aq_l;
    const ushort* Bh = mode ? Bk_h : Bq_h;
    const ushort* Bl = mode ? Bk_l : Bq_l;
    const float* bias = mode ? bk : bq;
    ushort* Chi = mode ? Ck_hi : Cq_hi;
    ushort* Clo = mode ? Ck_lo : Cq_lo;
    const int tn = blockIdx.x, tm = blockIdx.y;
    const int tid = threadIdx.x, lane = tid & 63, w = tid >> 6;
    const int lr = lane >> 4, lc = lane & 15;
    const int srow = lane >> 3;                       // 0..7 within chunk
    const int sblk = (lane & 7) ^ ((lane >> 3) & 7);  // swizzled 16B block
    f32x4 acc[8];
#pragma unroll
    for (int n = 0; n < 8; ++n) acc[n] = (f32x4){0.f, 0.f, 0.f, 0.f};

    for (int kt = 0; kt < DD; kt += 64) {
        __syncthreads();
#pragma unroll
        for (int i = 0; i < 2; ++i) {
            int ch = (w << 1) + i;                    // chunk 0..7 (8 rows each)
            int row = (ch << 3) + srow;               // 0..63
            size_t g = (size_t)(tm * 64 + row) * DD + kt + sblk * 8;
            gload16(Ah + g, Ash + ch * 512);
            gload16(Al + g, Asl + ch * 512);
        }
#pragma unroll
        for (int i = 0; i < 4; ++i) {
            int ch = (w << 2) + i;                    // chunk 0..15
            int row = (ch << 3) + srow;               // 0..127
            size_t g = (size_t)(tn * 128 + row) * DD + kt + sblk * 8;
            gload16(Bh + g, Bsh + ch * 512);
            gload16(Bl + g, Bsl + ch * 512);
        }
        __syncthreads();
#pragma unroll
        for (int t = 0; t < 2; ++t) {
            int aoff = SWZ(w * 16 + lc, t * 4 + lr);
            bf16x8 afh = *(const bf16x8*)(Ash + aoff);
            bf16x8 afl = *(const bf16x8*)(Asl + aoff);
#pragma unroll
            for (int n = 0; n < 8; ++n) {
                int boff = SWZ(n * 16 + lc, t * 4 + lr);
                bf16x8 bfh = *(const bf16x8*)(Bsh + boff);
                bf16x8 bfl = *(const bf16x8*)(Bsl + boff);
                acc[n] = __builtin_amdgcn_mfma_f32_16x16x32_bf16(afh, bfh, acc[n], 0, 0, 0);
                acc[n] = __builtin_amdgcn_mfma_f32_16x16x32_bf16(afh, bfl, acc[n], 0, 0, 0);
                acc[n] = __builtin_amdgcn_mfma_f32_16x16x32_bf16(afl, bfh, acc[n], 0, 0, 0);
            }
        }
    }
#pragma unroll
    for (int n = 0; n < 8; ++n) {
        int gcol = tn * 128 + n * 16 + lc;
#pragma unroll
        for (int r = 0; r < 4; ++r) {
            int grow = tm * 64 + w * 16 + lr * 4 + r;
            float v = acc[n][r] + bias[gcol];
            size_t idx = (size_t)grow * DD + gcol;
            ushort hh = f2bf(v);
            Chi[idx] = hh;
            Clo[idx] = f2bf(v - bf2f(hh));
            if (mode == 0) Cw[idx] = f2bf(v * wcomb[(grow >> 6) & 15]);
        }
    }
}

// ---------------- FAT kernel: gemm_comb (blocks 0..255) || attn (blocks 256..1279) ----
// attn LDS = 40 KB; XCD-locality decode: all 16 q-tiles of head bh share bh%8 -> same
// XCD L2 caches that head's kh/kl/kT (384 KB; 8 heads/XCD = 3 MB < 4 MB L2).
__global__ __launch_bounds__(256) void attn_comb(
    const ushort* __restrict__ qh_, const ushort* __restrict__ ql_,
    const ushort* __restrict__ kh_, const ushort* __restrict__ kl_,
    const ushort* __restrict__ kT_, const u64* __restrict__ mbits,
    float* __restrict__ ctx,
    const ushort* __restrict__ Aq, const ushort* __restrict__ Bk,
    const float* __restrict__ bcomb, float* __restrict__ probs) {
    __shared__ __align__(16) ushort shm[20480];  // 40,960 B
    const int bid = blockIdx.x;
    const int tid = threadIdx.x, lane = tid & 63, w = tid >> 6;
    const int lr = lane >> 4, lc = lane & 15;

    if (bid < 256) {
        // ---------------- combined-scores GEMM (swizzled staging; r13-r17-proven) -----
        ushort* As = shm;           // 128x64 swizzled (16 KB)
        ushort* Bs = shm + 8192;    // (16 KB)
        const int tn = bid & 7, tm = (bid >> 3) & 7, bz = bid >> 6;
        const ushort* Ab = Aq + (size_t)bz * SS * DD;
        const ushort* Bb = Bk + (size_t)bz * SS * DD;
        const int wm = w >> 1, wn = w & 1;
        f32x4 acc[4][4];
#pragma unroll
        for (int m = 0; m < 4; ++m)
#pragma unroll
            for (int n = 0; n < 4; ++n) acc[m][n] = (f32x4){0.f, 0.f, 0.f, 0.f};

        for (int h = 0; h < HH; ++h) {
            __syncthreads();
            const ushort* Asrc = Ab + (size_t)h * 65536 + tm * 8192;
            const ushort* Bsrc = Bb + (size_t)h * 65536 + tn * 8192;
#pragma unroll
            for (int i = 0; i < 4; ++i) {
                int ch = (w << 2) + i;                      // chunk 0..15 (1024B)
                int row = (ch << 3) + (lane >> 3);          // 0..127
                int blkk = (lane & 7) ^ ((lane >> 3) & 7);  // swizzled 16B block
                size_t g = (size_t)row * 64 + blkk * 8;
                gload16(Asrc + g, As + ch * 512);
                gload16(Bsrc + g, Bs + ch * 512);
            }
            __syncthreads();
#pragma unroll
            for (int t = 0; t < 2; ++t) {
                bf16x8 af[4], bfr[4];
#pragma unroll
                for (int m = 0; m < 4; ++m)
                    af[m] = *(const bf16x8*)(As + SWZ(wm * 64 + m * 16 + lc, t * 4 + lr));
#pragma unroll
                for (int n = 0; n < 4; ++n)
                    bfr[n] = *(const bf16x8*)(Bs + SWZ(wn * 64 + n * 16 + lc, t * 4 + lr));
#pragma unroll
                for (int m = 0; m < 4; ++m)
#pragma unroll
                    for (int n = 0; n < 4; ++n)
                        acc[m][n] = __builtin_amdgcn_mfma_f32_16x16x32_bf16(af[m], bfr[n], acc[m][n], 0, 0, 0);
            }
        }
        float b0 = bcomb[0];
#pragma unroll
        for (int m = 0; m < 4; ++m) {
            int grow0 = tm * 128 + wm * 64 + m * 16 + lr * 4;
#pragma unroll
            for (int n = 0; n < 4; ++n) {
                int gcol = tn * 128 + wn * 64 + n * 16 + lc;
#pragma unroll
                for (int r = 0; r < 4; ++r)
                    probs[(size_t)bz * SS * SS + (size_t)(grow0 + r) * SS + gcol] = acc[m][n][r] + b0;
            }
        }
        return;
    }

    // ---------------- flash attention (V = K): r17-proven body, XCD-local decode -----
    const int abid = bid - 256;
    const int qt = abid >> 6, bh = abid & 63;   // same-head q-tiles share bh%8 -> XCD
    const int b = bh >> 4, h = bh & 15;
    (void)h;
    const size_t headbase = (size_t)bh * (SS * 64);

    // LDS map (ushort units): KH[2] @ 0,4096 ; KL @ 8192 ; KT[2] @ 12288,16384
    auto KH = [&](int buf) -> ushort* { return shm + buf * 4096; };
    ushort* KL = shm + 8192;
    auto KT = [&](int buf) -> ushort* { return shm + 12288 + buf * 4096; };

    const int srow = lane >> 3;
    const int sblk = (lane & 7) ^ ((lane >> 3) & 7);
    auto stage_hT = [&](int buf, int kt) {
#pragma unroll
        for (int i = 0; i < 2; ++i) {
            int ch = (w << 1) + i;
            int row = (ch << 3) + srow;
            size_t g = ((size_t)bh * 16 + kt) * 4096 + (size_t)row * 64 + sblk * 8;
            gload16(kh_ + g, KH(buf) + ch * 512);
            gload16(kT_ + g, KT(buf) + ch * 512);
        }
    };
    auto stage_l = [&](int kt) {
#pragma unroll
        for (int i = 0; i < 2; ++i) {
            int ch = (w << 1) + i;
            int row = (ch << 3) + srow;
            size_t g = ((size_t)bh * 16 + kt) * 4096 + (size_t)row * 64 + sblk * 8;
            gload16(kl_ + g, KL + ch * 512);
        }
    };

    bf16x8 qfh[2], qfl[2];
    {
        size_t rowoff = headbase + (size_t)(qt * 64 + w * 16 + lc) * 64;
#pragma unroll
        for (int t = 0; t < 2; ++t) {
            qfh[t] = *(const bf16x8*)(qh_ + rowoff + t * 32 + lr * 8);
            qfl[t] = *(const bf16x8*)(ql_ + rowoff + t * 32 + lr * 8);
        }
    }
    f32x4 acc[4];
#pragma unroll
    for (int dt = 0; dt < 4; ++dt) acc[dt] = (f32x4){0.f, 0.f, 0.f, 0.f};
    float mrow[4] = {-3e38f, -3e38f, -3e38f, -3e38f};
    float lsum[4] = {0.f, 0.f, 0.f, 0.f};  // per-lane partial (scale is row-uniform)

    stage_hT(0, 0);
    stage_l(0);
    __syncthreads();
    int cur = 0;

    for (int kt = 0; kt < 16; ++kt) {
        if (kt < 15) stage_hT(cur ^ 1, kt + 1);  // kh/kT prefetch (hidden under compute)

        const ushort* Bh = KH(cur);
        const ushort* Vt = KT(cur);

        // QK^T (split precision): s = qh*kh + qh*kl + ql*kh
        f32x4 sc[4];
#pragma unroll
        for (int nt = 0; nt < 4; ++nt) {
            f32x4 z = (f32x4){0.f, 0.f, 0.f, 0.f};
            __builtin_amdgcn_s_setprio(1);
#pragma unroll
            for (int t = 0; t < 2; ++t) {
                bf16x8 kfh = *(const bf16x8*)(Bh + SWZ(nt * 16 + lc, t * 4 + lr));
                bf16x8 kfl = *(const bf16x8*)(KL + SWZ(nt * 16 + lc, t * 4 + lr));
                z = __builtin_amdgcn_mfma_f32_16x16x32_bf16(qfh[t], kfh, z, 0, 0, 0);
                z = __builtin_amdgcn_mfma_f32_16x16x32_bf16(qfh[t], kfl, z, 0, 0, 0);
                z = __builtin_amdgcn_mfma_f32_16x16x32_bf16(qfl[t], kfh, z, 0, 0, 0);
            }
            __builtin_amdgcn_s_setprio(0);
            sc[nt] = z;
        }

        // mask + online softmax: rmax shfl (proven), rsum deferred to per-lane partial
#pragma unroll
        for (int r = 0; r < 4; ++r) {
            u64 wbit = mbits[((size_t)b * SS + qt * 64 + w * 16 + lr * 4 + r) * 16 + kt];
            float rmax = -3e38f;
#pragma unroll
            for (int nt = 0; nt < 4; ++nt) {
                int kkloc = nt * 16 + lc;
                float v = sc[nt][r];
                v = ((wbit >> kkloc) & 1ULL) ? v : -3e38f;
                sc[nt][r] = v;
                rmax = fmaxf(rmax, v);
            }
#pragma unroll
            for (int d2 = 1; d2 < 16; d2 <<= 1) rmax = fmaxf(rmax, __shfl_xor(rmax, d2, 64));
            float mnew = fmaxf(mrow[r], rmax);
            float scale = __expf(mrow[r] - mnew);
            float rsum = 0.f;
#pragma unroll
            for (int nt = 0; nt < 4; ++nt) {
                float p = __expf(sc[nt][r] - mnew);
                sc[nt][r] = p;
                rsum += p;
            }
            lsum[r] = lsum[r] * scale + rsum;  // per-lane; summed across lanes at end
            mrow[r] = mnew;
#pragma unroll
            for (int dt = 0; dt < 4; ++dt) acc[dt][r] *= scale;
        }

        // RAW barrier: all waves' kh AND kl reads done (QK^T complete everywhere).
        // (No vmcnt drain -> the stage_hT prefetch stays in flight.)
        __builtin_amdgcn_s_barrier();
        __builtin_amdgcn_sched_barrier(0);

        // kl for NEXT tile -> single KL buffer (safe after barrier); overlaps P+PV.
        if (kt < 15) stage_l(kt + 1);

        // P -> aliased kh slice (wave-private 16x64, SWZ-swizzled), RNE pack (proven)
        ushort* P = KH(cur) + w * 1024;
#pragma unroll
        for (int nt = 0; nt < 4; ++nt)
#pragma unroll
            for (int r = 0; r < 4; ++r) {
                int lrow = lr * 4 + r;
                P[SWZ(lrow, nt * 2 + (lc >> 3)) + (lc & 7)] = f2bf(sc[nt][r]);
            }
        asm volatile("s_waitcnt lgkmcnt(0)" ::: "memory");
        __builtin_amdgcn_sched_barrier(0);

        bf16x8 pf[2];
#pragma unroll
        for (int t = 0; t < 2; ++t)
            pf[t] = *(const bf16x8*)(P + SWZ(lc, t * 4 + lr));

        // PV: context += P @ K_tile (V = K hi, from pre-transposed kT)
        __builtin_amdgcn_s_setprio(1);
#pragma unroll
        for (int dt = 0; dt < 4; ++dt) {
#pragma unroll
            for (int t = 0; t < 2; ++t) {
                bf16x8 vf = *(const bf16x8*)(Vt + SWZ(dt * 16 + lc, t * 4 + lr));
                acc[dt] = __builtin_amdgcn_mfma_f32_16x16x32_bf16(pf[t], vf, acc[dt], 0, 0, 0);
            }
        }
        __builtin_amdgcn_s_setprio(0);

        if (kt < 15) __syncthreads();  // drains vmcnt (stage_hT + stage_l) + syncs
        cur ^= 1;
    }

    // epilogue: one lsum reduction across the 16-lane row group (proven shfl butterfly)
#pragma unroll
    for (int r = 0; r < 4; ++r) {
#pragma unroll
        for (int d2 = 1; d2 < 16; d2 <<= 1) lsum[r] += __shfl_xor(lsum[r], d2, 64);
        float inv = (lsum[r] > 0.f) ? 1.f / lsum[r] : 0.f;
        int q = qt * 64 + w * 16 + lr * 4 + r;
#pragma unroll
        for (int dt = 0; dt < 4; ++dt)
            ctx[(((size_t)bh) * SS + q) * 64 + dt * 16 + lc] = acc[dt][r] * inv;
    }
}

// ---------------- row softmax for probs ----------------
__global__ __launch_bounds__(256) void softmax_rows(float* __restrict__ data) {
    int w = threadIdx.x >> 6, lane = threadIdx.x & 63;
    float* p = data + ((size_t)blockIdx.x * 4 + w) * SS;
    float4 v[4];
    float mx = -3e38f;
#pragma unroll
    for (int i = 0; i < 4; ++i) {
        v[i] = *(const float4*)(p + i * 256 + lane * 4);
        mx = fmaxf(mx, fmaxf(fmaxf(v[i].x, v[i].y), fmaxf(v[i].z, v[i].w)));
    }
#pragma unroll
    for (int d2 = 1; d2 < 64; d2 <<= 1) mx = fmaxf(mx, __shfl_xor(mx, d2, 64));
    float sum = 0.f;
#pragma unroll
    for (int i = 0; i < 4; ++i) {
        v[i].x = __expf(v[i].x - mx);
        v[i].y = __expf(v[i].y - mx);
        v[i].z = __expf(v[i].z - mx);
        v[i].w = __expf(v[i].w - mx);
        sum += v[i].x + v[i].y + v[i].z + v[i].w;
    }
#pragma unroll
    for (int d2 = 1; d2 < 64; d2 <<= 1) sum += __shfl_xor(sum, d2, 64);
    float inv = 1.f / sum;
#pragma unroll
    for (int i = 0; i < 4; ++i) {
        v[i].x *= inv; v[i].y *= inv; v[i].z *= inv; v[i].w *= inv;
        *(float4*)(p + i * 256 + lane * 4) = v[i];
    }
}

extern "C" void kernel_launch(void* const* d_in, const int* in_sizes, int n_in,
                              void* d_out, int out_size, void* d_ws, size_t ws_size,
                              hipStream_t stream) {
    const float* query = (const float*)d_in[0];
    const float* key   = (const float*)d_in[1];
    const int*   mask  = (const int*)d_in[2];
    const float* Wq    = (const float*)d_in[3];
    const float* bq    = (const float*)d_in[4];
    const float* Wk    = (const float*)d_in[5];
    const float* bk    = (const float*)d_in[6];
    const float* wcomb = (const float*)d_in[7];
    const float* bcomb = (const float*)d_in[8];
    float* probs = (float*)d_out;                          // (B,S,S)
    float* ctx   = (float*)d_out + (size_t)BB * SS * SS;   // (B,H,S,DK) flat

    char* ws = (char*)d_ws;
    const size_t MB = 1ull << 20;
    ushort* query_hi = (ushort*)(ws);             // [0,8)
    ushort* query_lo = (ushort*)(ws + 8 * MB);    // [8,16)
    ushort* key_hi   = (ushort*)(ws + 16 * MB);   // [16,24)
    ushort* key_lo   = (ushort*)(ws + 24 * MB);   // [24,32)
    ushort* WqTh     = (ushort*)(ws + 32 * MB);   // [32,34)
    ushort* WqTl     = (ushort*)(ws + 34 * MB);   // [34,36)
    ushort* WkTh     = (ushort*)(ws + 36 * MB);   // [36,38)
    ushort* WkTl     = (ushort*)(ws + 38 * MB);   // [38,40)
    ushort* qw_bf    = (ushort*)(ws + 40 * MB);   // [40,48)
    ushort* q_hi     = (ushort*)(ws + 48 * MB);   // [48,56)
    ushort* q_lo     = (ushort*)(ws + 56 * MB);   // [56,64)
    u64*    mbits    = (u64*)(ws + 64 * MB);      // [64,64.5)
    ushort* kT       = (ushort*)(ws + 65 * MB);   // [65,73)

    const bool bigws = ws_size >= 90 * MB;
    ushort* k_hi = bigws ? (ushort*)(ws + 73 * MB) : (ushort*)(ws);
    ushort* k_lo = bigws ? (ushort*)(ws + 81 * MB) : (ushort*)(ws + 8 * MB);

    cvt_split2<<<8192, 256, 0, stream>>>(query, key, query_hi, query_lo, key_hi, key_lo);
    transposeW_split<<<dim3(16, 16, 2), 256, 0, stream>>>(Wq, Wk, WqTh, WqTl, WkTh, WkTl);
    pack_mask<<<16384, 256, 0, stream>>>(mask, mbits, BB * SS * (SS / 64));

    if (bigws) {
        gemm_proj_f<<<dim3(8, 64, 2), 256, 0, stream>>>(
            query_hi, query_lo, key_hi, key_lo, WqTh, WqTl, WkTh, WkTl,
            bq, bk, wcomb, q_hi, q_lo, qw_bf, k_hi, k_lo, 0);
    } else {
        gemm_proj_f<<<dim3(8, 64, 1), 256, 0, stream>>>(
            query_hi, query_lo, key_hi, key_lo, WqTh, WqTl, WkTh, WkTl,
            bq, bk, wcomb, q_hi, q_lo, qw_bf, k_hi, k_lo, 0);
        gemm_proj_f<<<dim3(8, 64, 1), 256, 0, stream>>>(
            query_hi, query_lo, key_hi, key_lo, WqTh, WqTl, WkTh, WkTl,
            bq, bk, wcomb, q_hi, q_lo, qw_bf, k_hi, k_lo, 1);
    }

    transposeK<<<1024, 256, 0, stream>>>(k_hi, kT);

    // fat kernel: blocks 0..255 = combined-scores GEMM, 256..1279 = attention
    attn_comb<<<1280, 256, 0, stream>>>(q_hi, q_lo, k_hi, k_lo, kT, mbits, ctx,
                                        qw_bf, k_hi, bcomb, probs);

    softmax_rows<<<1024, 256, 0, stream>>>(probs);
    (void)in_sizes; (void)n_in; (void)out_size;
}

// Round 19
// 190.979 us; speedup vs baseline: 1.0769x; 1.0262x over previous
//
#include <hip/hip_runtime.h>
#include <hip/hip_bf16.h>

#define BB 4
#define SS 1024
#define DD 1024
#define HH 16

typedef __attribute__((ext_vector_type(8))) short bf16x8;
typedef __attribute__((ext_vector_type(4))) float f32x4;
typedef unsigned int u32;
typedef unsigned long long u64;

__device__ __forceinline__ ushort f2bf(float f) {
    u32 u = __builtin_bit_cast(u32, f);
    u32 r = (u + 0x7fffu + ((u >> 16) & 1u)) >> 16;
    return (ushort)r;
}
__device__ __forceinline__ float bf2f(ushort h) {
    return __builtin_bit_cast(float, (u32)h << 16);
}

__device__ __forceinline__ void gload16(const ushort* g, ushort* l) {
    __builtin_amdgcn_global_load_lds(
        (const __attribute__((address_space(1))) u32*)(const void*)g,
        (__attribute__((address_space(3))) u32*)(void*)l, 16, 0, 0);
}

// ---------------- fused prep: cvt (0..8191) | transposeW (8192..8703) | pack (8704..) --
__global__ __launch_bounds__(256) void prep_fused(
    const float* __restrict__ q, const float* __restrict__ k,
    ushort* __restrict__ qh, ushort* __restrict__ ql,
    ushort* __restrict__ kh, ushort* __restrict__ kl,
    const float* __restrict__ Wq, const float* __restrict__ Wk,
    ushort* __restrict__ WqTh, ushort* __restrict__ WqTl,
    ushort* __restrict__ WkTh, ushort* __restrict__ WkTl,
    const int* __restrict__ mask, u64* __restrict__ bits) {
    __shared__ float tile[64][65];
    int bid = blockIdx.x;
    int tid = threadIdx.x;

    if (bid < 8192) {
        // ---- cvt_split2 body (r13-r18-proven) ----
        const float* in;
        ushort *hi, *lo;
        if (bid < 4096) { in = q; hi = qh; lo = ql; }
        else            { in = k; hi = kh; lo = kl; bid -= 4096; }
        int i = (bid * 256 + tid) * 4;
        float4 v = *(const float4*)(in + i);
        ushort4 h, l;
        float* pv = (float*)&v;
        ushort* ph = (ushort*)&h;
        ushort* pl = (ushort*)&l;
#pragma unroll
        for (int j = 0; j < 4; ++j) {
            ushort hh = f2bf(pv[j]);
            ph[j] = hh;
            pl[j] = f2bf(pv[j] - bf2f(hh));
        }
        *(ushort4*)(hi + i) = h;
        *(ushort4*)(lo + i) = l;
        return;
    }
    if (bid < 8704) {
        // ---- transposeW_split body (r13-r18-proven; decode dim3(16,16,2)) ----
        int tw = bid - 8192;
        int z = tw >> 8;
        int nb = (tw & 15) * 64, kb = ((tw >> 4) & 15) * 64;
        const float* W = z ? Wk : Wq;
        ushort* WTh = z ? WkTh : WqTh;
        ushort* WTl = z ? WkTl : WqTl;
        int tx = tid & 63, ty = tid >> 6;
#pragma unroll
        for (int i = 0; i < 16; ++i) {
            int klr = ty * 16 + i;
            tile[klr][tx] = W[(size_t)(kb + klr) * DD + nb + tx];
        }
        __syncthreads();
#pragma unroll
        for (int i = 0; i < 16; ++i) {
            int nl = ty * 16 + i;
            float v = tile[tx][nl];
            ushort hh = f2bf(v);
            size_t idx = (size_t)(nb + nl) * DD + kb + tx;
            WTh[idx] = hh;
            WTl[idx] = f2bf(v - bf2f(hh));
        }
        return;
    }
    // ---- pack_mask body (r13-r18-proven) ----
    int pm = bid - 8704;
    int gw = (int)((pm * 256 + tid) >> 6);
    int lane = tid & 63;
    int v = mask[(size_t)gw * 64 + lane];
    u64 m = __ballot(v != 0);
    if (lane == 0) bits[gw] = m;
}

// swizzled LDS frag address (ushort units): row rr, 16B-block bi
#define SWZ(rr, bi) (((rr) << 6) + ((((bi) ^ ((rr) & 7))) << 3))

// ---------------- transpose k_hi per head-tile into tiled kT ----------------
__global__ __launch_bounds__(256) void transposeK(const ushort* __restrict__ kh,
                                                  ushort* __restrict__ kT) {
    __shared__ ushort t[64 * 66];
    int blk = blockIdx.x;
    const ushort* src = kh + (size_t)blk * 4096;
    ushort* dst = kT + (size_t)blk * 4096;
    int tid = threadIdx.x;
#pragma unroll
    for (int i = 0; i < 2; ++i) {
        int c = tid + 256 * i;
        int r = c >> 3, col = (c & 7) << 3;
        uint4 v = *(const uint4*)(src + (size_t)c * 8);
        const uint* pv = (const uint*)&v;
        *(uint*)(t + r * 66 + col + 0) = pv[0];
        *(uint*)(t + r * 66 + col + 2) = pv[1];
        *(uint*)(t + r * 66 + col + 4) = pv[2];
        *(uint*)(t + r * 66 + col + 6) = pv[3];
    }
    __syncthreads();
#pragma unroll
    for (int i = 0; i < 2; ++i) {
        int c = tid + 256 * i;
        int d = c >> 3, k0 = (c & 7) << 3;
        uint4 o;
        ushort* po = (ushort*)&o;
#pragma unroll
        for (int j = 0; j < 8; ++j) po[j] = t[(k0 + j) * 66 + d];
        *(uint4*)(dst + d * 64 + k0) = o;
    }
}

// ---------------- split-precision projection GEMM, q & k fused via blockIdx.z ----------
__global__ __launch_bounds__(256) void gemm_proj_f(
    const ushort* __restrict__ Aq_h, const ushort* __restrict__ Aq_l,
    const ushort* __restrict__ Ak_h, const ushort* __restrict__ Ak_l,
    const ushort* __restrict__ Bq_h, const ushort* __restrict__ Bq_l,
    const ushort* __restrict__ Bk_h, const ushort* __restrict__ Bk_l,
    const float* __restrict__ bq, const float* __restrict__ bk,
    const float* __restrict__ wcomb,
    ushort* __restrict__ Cq_hi, ushort* __restrict__ Cq_lo, ushort* __restrict__ Cw,
    ushort* __restrict__ Ck_hi, ushort* __restrict__ Ck_lo, int mode_base) {
    __shared__ __align__(16) ushort Ash[64 * 64];
    __shared__ __align__(16) ushort Asl[64 * 64];
    __shared__ __align__(16) ushort Bsh[128 * 64];
    __shared__ __align__(16) ushort Bsl[128 * 64];
    const int mode = blockIdx.z + mode_base;
    const ushort* Ah = mode ? Ak_h : Aq_h;
    const ushort* Al = mode ? Ak_l : Aq_l;
    const ushort* Bh = mode ? Bk_h : Bq_h;
    const ushort* Bl = mode ? Bk_l : Bq_l;
    const float* bias = mode ? bk : bq;
    ushort* Chi = mode ? Ck_hi : Cq_hi;
    ushort* Clo = mode ? Ck_lo : Cq_lo;
    const int tn = blockIdx.x, tm = blockIdx.y;
    const int tid = threadIdx.x, lane = tid & 63, w = tid >> 6;
    const int lr = lane >> 4, lc = lane & 15;
    const int srow = lane >> 3;                       // 0..7 within chunk
    const int sblk = (lane & 7) ^ ((lane >> 3) & 7);  // swizzled 16B block
    f32x4 acc[8];
#pragma unroll
    for (int n = 0; n < 8; ++n) acc[n] = (f32x4){0.f, 0.f, 0.f, 0.f};

    for (int kt = 0; kt < DD; kt += 64) {
        __syncthreads();
#pragma unroll
        for (int i = 0; i < 2; ++i) {
            int ch = (w << 1) + i;                    // chunk 0..7 (8 rows each)
            int row = (ch << 3) + srow;               // 0..63
            size_t g = (size_t)(tm * 64 + row) * DD + kt + sblk * 8;
            gload16(Ah + g, Ash + ch * 512);
            gload16(Al + g, Asl + ch * 512);
        }
#pragma unroll
        for (int i = 0; i < 4; ++i) {
            int ch = (w << 2) + i;                    // chunk 0..15
            int row = (ch << 3) + srow;               // 0..127
            size_t g = (size_t)(tn * 128 + row) * DD + kt + sblk * 8;
            gload16(Bh + g, Bsh + ch * 512);
            gload16(Bl + g, Bsl + ch * 512);
        }
        __syncthreads();
#pragma unroll
        for (int t = 0; t < 2; ++t) {
            int aoff = SWZ(w * 16 + lc, t * 4 + lr);
            bf16x8 afh = *(const bf16x8*)(Ash + aoff);
            bf16x8 afl = *(const bf16x8*)(Asl + aoff);
#pragma unroll
            for (int n = 0; n < 8; ++n) {
                int boff = SWZ(n * 16 + lc, t * 4 + lr);
                bf16x8 bfh = *(const bf16x8*)(Bsh + boff);
                bf16x8 bfl = *(const bf16x8*)(Bsl + boff);
                acc[n] = __builtin_amdgcn_mfma_f32_16x16x32_bf16(afh, bfh, acc[n], 0, 0, 0);
                acc[n] = __builtin_amdgcn_mfma_f32_16x16x32_bf16(afh, bfl, acc[n], 0, 0, 0);
                acc[n] = __builtin_amdgcn_mfma_f32_16x16x32_bf16(afl, bfh, acc[n], 0, 0, 0);
            }
        }
    }
#pragma unroll
    for (int n = 0; n < 8; ++n) {
        int gcol = tn * 128 + n * 16 + lc;
#pragma unroll
        for (int r = 0; r < 4; ++r) {
            int grow = tm * 64 + w * 16 + lr * 4 + r;
            float v = acc[n][r] + bias[gcol];
            size_t idx = (size_t)grow * DD + gcol;
            ushort hh = f2bf(v);
            Chi[idx] = hh;
            Clo[idx] = f2bf(v - bf2f(hh));
            if (mode == 0) Cw[idx] = f2bf(v * wcomb[(grow >> 6) & 15]);
        }
    }
}

// ---------------- FAT kernel: gemm_comb (blocks 0..255) || attn (blocks 256..1279) ----
// attn LDS = 40 KB; XCD-locality decode: all 16 q-tiles of head bh share bh%8 -> same
// XCD L2 caches that head's kh/kl/kT (384 KB; 8 heads/XCD = 3 MB < 4 MB L2).
__global__ __launch_bounds__(256) void attn_comb(
    const ushort* __restrict__ qh_, const ushort* __restrict__ ql_,
    const ushort* __restrict__ kh_, const ushort* __restrict__ kl_,
    const ushort* __restrict__ kT_, const u64* __restrict__ mbits,
    float* __restrict__ ctx,
    const ushort* __restrict__ Aq, const ushort* __restrict__ Bk,
    const float* __restrict__ bcomb, float* __restrict__ probs) {
    __shared__ __align__(16) ushort shm[20480];  // 40,960 B
    const int bid = blockIdx.x;
    const int tid = threadIdx.x, lane = tid & 63, w = tid >> 6;
    const int lr = lane >> 4, lc = lane & 15;

    if (bid < 256) {
        // ---------------- combined-scores GEMM (swizzled staging; r13-r18-proven) -----
        ushort* As = shm;           // 128x64 swizzled (16 KB)
        ushort* Bs = shm + 8192;    // (16 KB)
        const int tn = bid & 7, tm = (bid >> 3) & 7, bz = bid >> 6;
        const ushort* Ab = Aq + (size_t)bz * SS * DD;
        const ushort* Bb = Bk + (size_t)bz * SS * DD;
        const int wm = w >> 1, wn = w & 1;
        f32x4 acc[4][4];
#pragma unroll
        for (int m = 0; m < 4; ++m)
#pragma unroll
            for (int n = 0; n < 4; ++n) acc[m][n] = (f32x4){0.f, 0.f, 0.f, 0.f};

        for (int h = 0; h < HH; ++h) {
            __syncthreads();
            const ushort* Asrc = Ab + (size_t)h * 65536 + tm * 8192;
            const ushort* Bsrc = Bb + (size_t)h * 65536 + tn * 8192;
#pragma unroll
            for (int i = 0; i < 4; ++i) {
                int ch = (w << 2) + i;                      // chunk 0..15 (1024B)
                int row = (ch << 3) + (lane >> 3);          // 0..127
                int blkk = (lane & 7) ^ ((lane >> 3) & 7);  // swizzled 16B block
                size_t g = (size_t)row * 64 + blkk * 8;
                gload16(Asrc + g, As + ch * 512);
                gload16(Bsrc + g, Bs + ch * 512);
            }
            __syncthreads();
#pragma unroll
            for (int t = 0; t < 2; ++t) {
                bf16x8 af[4], bfr[4];
#pragma unroll
                for (int m = 0; m < 4; ++m)
                    af[m] = *(const bf16x8*)(As + SWZ(wm * 64 + m * 16 + lc, t * 4 + lr));
#pragma unroll
                for (int n = 0; n < 4; ++n)
                    bfr[n] = *(const bf16x8*)(Bs + SWZ(wn * 64 + n * 16 + lc, t * 4 + lr));
#pragma unroll
                for (int m = 0; m < 4; ++m)
#pragma unroll
                    for (int n = 0; n < 4; ++n)
                        acc[m][n] = __builtin_amdgcn_mfma_f32_16x16x32_bf16(af[m], bfr[n], acc[m][n], 0, 0, 0);
            }
        }
        float b0 = bcomb[0];
#pragma unroll
        for (int m = 0; m < 4; ++m) {
            int grow0 = tm * 128 + wm * 64 + m * 16 + lr * 4;
#pragma unroll
            for (int n = 0; n < 4; ++n) {
                int gcol = tn * 128 + wn * 64 + n * 16 + lc;
#pragma unroll
                for (int r = 0; r < 4; ++r)
                    probs[(size_t)bz * SS * SS + (size_t)(grow0 + r) * SS + gcol] = acc[m][n][r] + b0;
            }
        }
        return;
    }

    // ---------------- flash attention (V = K): r18-proven body, XCD-local decode -----
    const int abid = bid - 256;
    const int qt = abid >> 6, bh = abid & 63;   // same-head q-tiles share bh%8 -> XCD
    const int b = bh >> 4;
    const size_t headbase = (size_t)bh * (SS * 64);

    // LDS map (ushort units): KH[2] @ 0,4096 ; KL @ 8192 ; KT[2] @ 12288,16384
    auto KH = [&](int buf) -> ushort* { return shm + buf * 4096; };
    ushort* KL = shm + 8192;
    auto KT = [&](int buf) -> ushort* { return shm + 12288 + buf * 4096; };

    const int srow = lane >> 3;
    const int sblk = (lane & 7) ^ ((lane >> 3) & 7);
    auto stage_hT = [&](int buf, int kt) {
#pragma unroll
        for (int i = 0; i < 2; ++i) {
            int ch = (w << 1) + i;
            int row = (ch << 3) + srow;
            size_t g = ((size_t)bh * 16 + kt) * 4096 + (size_t)row * 64 + sblk * 8;
            gload16(kh_ + g, KH(buf) + ch * 512);
            gload16(kT_ + g, KT(buf) + ch * 512);
        }
    };
    auto stage_l = [&](int kt) {
#pragma unroll
        for (int i = 0; i < 2; ++i) {
            int ch = (w << 1) + i;
            int row = (ch << 3) + srow;
            size_t g = ((size_t)bh * 16 + kt) * 4096 + (size_t)row * 64 + sblk * 8;
            gload16(kl_ + g, KL + ch * 512);
        }
    };

    bf16x8 qfh[2], qfl[2];
    {
        size_t rowoff = headbase + (size_t)(qt * 64 + w * 16 + lc) * 64;
#pragma unroll
        for (int t = 0; t < 2; ++t) {
            qfh[t] = *(const bf16x8*)(qh_ + rowoff + t * 32 + lr * 8);
            qfl[t] = *(const bf16x8*)(ql_ + rowoff + t * 32 + lr * 8);
        }
    }
    f32x4 acc[4];
#pragma unroll
    for (int dt = 0; dt < 4; ++dt) acc[dt] = (f32x4){0.f, 0.f, 0.f, 0.f};
    float mrow[4] = {-3e38f, -3e38f, -3e38f, -3e38f};
    float lsum[4] = {0.f, 0.f, 0.f, 0.f};  // per-lane partial (scale is row-uniform)

    stage_hT(0, 0);
    stage_l(0);
    __syncthreads();
    int cur = 0;

    for (int kt = 0; kt < 16; ++kt) {
        if (kt < 15) stage_hT(cur ^ 1, kt + 1);  // kh/kT prefetch (hidden under compute)

        const ushort* Bh = KH(cur);
        const ushort* Vt = KT(cur);

        // QK^T (split precision): s = qh*kh + qh*kl + ql*kh
        f32x4 sc[4];
#pragma unroll
        for (int nt = 0; nt < 4; ++nt) {
            f32x4 z = (f32x4){0.f, 0.f, 0.f, 0.f};
            __builtin_amdgcn_s_setprio(1);
#pragma unroll
            for (int t = 0; t < 2; ++t) {
                bf16x8 kfh = *(const bf16x8*)(Bh + SWZ(nt * 16 + lc, t * 4 + lr));
                bf16x8 kfl = *(const bf16x8*)(KL + SWZ(nt * 16 + lc, t * 4 + lr));
                z = __builtin_amdgcn_mfma_f32_16x16x32_bf16(qfh[t], kfh, z, 0, 0, 0);
                z = __builtin_amdgcn_mfma_f32_16x16x32_bf16(qfh[t], kfl, z, 0, 0, 0);
                z = __builtin_amdgcn_mfma_f32_16x16x32_bf16(qfl[t], kfh, z, 0, 0, 0);
            }
            __builtin_amdgcn_s_setprio(0);
            sc[nt] = z;
        }

        // mask + online softmax: rmax shfl (proven), rsum deferred to per-lane partial
#pragma unroll
        for (int r = 0; r < 4; ++r) {
            u64 wbit = mbits[((size_t)b * SS + qt * 64 + w * 16 + lr * 4 + r) * 16 + kt];
            float rmax = -3e38f;
#pragma unroll
            for (int nt = 0; nt < 4; ++nt) {
                int kkloc = nt * 16 + lc;
                float v = sc[nt][r];
                v = ((wbit >> kkloc) & 1ULL) ? v : -3e38f;
                sc[nt][r] = v;
                rmax = fmaxf(rmax, v);
            }
#pragma unroll
            for (int d2 = 1; d2 < 16; d2 <<= 1) rmax = fmaxf(rmax, __shfl_xor(rmax, d2, 64));
            float mnew = fmaxf(mrow[r], rmax);
            float scale = __expf(mrow[r] - mnew);
            float rsum = 0.f;
#pragma unroll
            for (int nt = 0; nt < 4; ++nt) {
                float p = __expf(sc[nt][r] - mnew);
                sc[nt][r] = p;
                rsum += p;
            }
            lsum[r] = lsum[r] * scale + rsum;  // per-lane; summed across lanes at end
            mrow[r] = mnew;
#pragma unroll
            for (int dt = 0; dt < 4; ++dt) acc[dt][r] *= scale;
        }

        // RAW barrier: all waves' kh AND kl reads done (QK^T complete everywhere).
        // (No vmcnt drain -> the stage_hT prefetch stays in flight.)
        __builtin_amdgcn_s_barrier();
        __builtin_amdgcn_sched_barrier(0);

        // kl for NEXT tile -> single KL buffer (safe after barrier); overlaps P+PV.
        if (kt < 15) stage_l(kt + 1);

        // P -> aliased kh slice (wave-private 16x64, SWZ-swizzled), RNE pack (proven)
        ushort* P = KH(cur) + w * 1024;
#pragma unroll
        for (int nt = 0; nt < 4; ++nt)
#pragma unroll
            for (int r = 0; r < 4; ++r) {
                int lrow = lr * 4 + r;
                P[SWZ(lrow, nt * 2 + (lc >> 3)) + (lc & 7)] = f2bf(sc[nt][r]);
            }
        asm volatile("s_waitcnt lgkmcnt(0)" ::: "memory");
        __builtin_amdgcn_sched_barrier(0);

        bf16x8 pf[2];
#pragma unroll
        for (int t = 0; t < 2; ++t)
            pf[t] = *(const bf16x8*)(P + SWZ(lc, t * 4 + lr));

        // PV: context += P @ K_tile (V = K hi, from pre-transposed kT)
        __builtin_amdgcn_s_setprio(1);
#pragma unroll
        for (int dt = 0; dt < 4; ++dt) {
#pragma unroll
            for (int t = 0; t < 2; ++t) {
                bf16x8 vf = *(const bf16x8*)(Vt + SWZ(dt * 16 + lc, t * 4 + lr));
                acc[dt] = __builtin_amdgcn_mfma_f32_16x16x32_bf16(pf[t], vf, acc[dt], 0, 0, 0);
            }
        }
        __builtin_amdgcn_s_setprio(0);

        if (kt < 15) __syncthreads();  // drains vmcnt (stage_hT + stage_l) + syncs
        cur ^= 1;
    }

    // epilogue: one lsum reduction across the 16-lane row group (proven shfl butterfly)
#pragma unroll
    for (int r = 0; r < 4; ++r) {
#pragma unroll
        for (int d2 = 1; d2 < 16; d2 <<= 1) lsum[r] += __shfl_xor(lsum[r], d2, 64);
        float inv = (lsum[r] > 0.f) ? 1.f / lsum[r] : 0.f;
        int q = qt * 64 + w * 16 + lr * 4 + r;
#pragma unroll
        for (int dt = 0; dt < 4; ++dt)
            ctx[(((size_t)bh) * SS + q) * 64 + dt * 16 + lc] = acc[dt][r] * inv;
    }
}

// ---------------- row softmax for probs ----------------
__global__ __launch_bounds__(256) void softmax_rows(float* __restrict__ data) {
    int w = threadIdx.x >> 6, lane = threadIdx.x & 63;
    float* p = data + ((size_t)blockIdx.x * 4 + w) * SS;
    float4 v[4];
    float mx = -3e38f;
#pragma unroll
    for (int i = 0; i < 4; ++i) {
        v[i] = *(const float4*)(p + i * 256 + lane * 4);
        mx = fmaxf(mx, fmaxf(fmaxf(v[i].x, v[i].y), fmaxf(v[i].z, v[i].w)));
    }
#pragma unroll
    for (int d2 = 1; d2 < 64; d2 <<= 1) mx = fmaxf(mx, __shfl_xor(mx, d2, 64));
    float sum = 0.f;
#pragma unroll
    for (int i = 0; i < 4; ++i) {
        v[i].x = __expf(v[i].x - mx);
        v[i].y = __expf(v[i].y - mx);
        v[i].z = __expf(v[i].z - mx);
        v[i].w = __expf(v[i].w - mx);
        sum += v[i].x + v[i].y + v[i].z + v[i].w;
    }
#pragma unroll
    for (int d2 = 1; d2 < 64; d2 <<= 1) sum += __shfl_xor(sum, d2, 64);
    float inv = 1.f / sum;
#pragma unroll
    for (int i = 0; i < 4; ++i) {
        v[i].x *= inv; v[i].y *= inv; v[i].z *= inv; v[i].w *= inv;
        *(float4*)(p + i * 256 + lane * 4) = v[i];
    }
}

extern "C" void kernel_launch(void* const* d_in, const int* in_sizes, int n_in,
                              void* d_out, int out_size, void* d_ws, size_t ws_size,
                              hipStream_t stream) {
    const float* query = (const float*)d_in[0];
    const float* key   = (const float*)d_in[1];
    const int*   mask  = (const int*)d_in[2];
    const float* Wq    = (const float*)d_in[3];
    const float* bq    = (const float*)d_in[4];
    const float* Wk    = (const float*)d_in[5];
    const float* bk    = (const float*)d_in[6];
    const float* wcomb = (const float*)d_in[7];
    const float* bcomb = (const float*)d_in[8];
    float* probs = (float*)d_out;                          // (B,S,S)
    float* ctx   = (float*)d_out + (size_t)BB * SS * SS;   // (B,H,S,DK) flat

    char* ws = (char*)d_ws;
    const size_t MB = 1ull << 20;
    ushort* query_hi = (ushort*)(ws);             // [0,8)
    ushort* query_lo = (ushort*)(ws + 8 * MB);    // [8,16)
    ushort* key_hi   = (ushort*)(ws + 16 * MB);   // [16,24)
    ushort* key_lo   = (ushort*)(ws + 24 * MB);   // [24,32)
    ushort* WqTh     = (ushort*)(ws + 32 * MB);   // [32,34)
    ushort* WqTl     = (ushort*)(ws + 34 * MB);   // [34,36)
    ushort* WkTh     = (ushort*)(ws + 36 * MB);   // [36,38)
    ushort* WkTl     = (ushort*)(ws + 38 * MB);   // [38,40)
    ushort* qw_bf    = (ushort*)(ws + 40 * MB);   // [40,48)
    ushort* q_hi     = (ushort*)(ws + 48 * MB);   // [48,56)
    ushort* q_lo     = (ushort*)(ws + 56 * MB);   // [56,64)
    u64*    mbits    = (u64*)(ws + 64 * MB);      // [64,64.5)
    ushort* kT       = (ushort*)(ws + 65 * MB);   // [65,73)

    const bool bigws = ws_size >= 90 * MB;
    ushort* k_hi = bigws ? (ushort*)(ws + 73 * MB) : (ushort*)(ws);
    ushort* k_lo = bigws ? (ushort*)(ws + 81 * MB) : (ushort*)(ws + 8 * MB);

    // fused prep: cvt (8192) + transposeW (512) + pack_mask (16384) in one launch
    prep_fused<<<25088, 256, 0, stream>>>(query, key, query_hi, query_lo, key_hi, key_lo,
                                          Wq, Wk, WqTh, WqTl, WkTh, WkTl, mask, mbits);

    if (bigws) {
        gemm_proj_f<<<dim3(8, 64, 2), 256, 0, stream>>>(
            query_hi, query_lo, key_hi, key_lo, WqTh, WqTl, WkTh, WkTl,
            bq, bk, wcomb, q_hi, q_lo, qw_bf, k_hi, k_lo, 0);
    } else {
        gemm_proj_f<<<dim3(8, 64, 1), 256, 0, stream>>>(
            query_hi, query_lo, key_hi, key_lo, WqTh, WqTl, WkTh, WkTl,
            bq, bk, wcomb, q_hi, q_lo, qw_bf, k_hi, k_lo, 0);
        gemm_proj_f<<<dim3(8, 64, 1), 256, 0, stream>>>(
            query_hi, query_lo, key_hi, key_lo, WqTh, WqTl, WkTh, WkTl,
            bq, bk, wcomb, q_hi, q_lo, qw_bf, k_hi, k_lo, 1);
    }

    transposeK<<<1024, 256, 0, stream>>>(k_hi, kT);

    // fat kernel: blocks 0..255 = combined-scores GEMM, 256..1279 = attention
    attn_comb<<<1280, 256, 0, stream>>>(q_hi, q_lo, k_hi, k_lo, kT, mbits, ctx,
                                        qw_bf, k_hi, bcomb, probs);

    softmax_rows<<<1024, 256, 0, stream>>>(probs);
    (void)in_sizes; (void)n_in; (void)out_size;
}